// Round 2
// baseline (27951.193 us; speedup 1.0000x reference)
//
#include <hip/hip_runtime.h>
#include <hip/hip_bf16.h>
#include <stdint.h>

#define DIMM   768
#define NLAYER 12
#define DST    64
#define DINNER 1536
#define NH     24
#define CONVD  1664
#define DINP   3224
#define NB     4
#define LL     2048
#define ROWS   (NB*LL)      // 8192
#define VOC    2048

typedef float f32x4 __attribute__((ext_vector_type(4)));
typedef short s16x8 __attribute__((ext_vector_type(8)));

// ---------- helpers ----------
__device__ __forceinline__ unsigned short f2bf(float f) {
  unsigned int u = __float_as_uint(f);
  u = (u + 0x7fffu + ((u >> 16) & 1u)) >> 16;   // RNE
  return (unsigned short)u;
}

__device__ __forceinline__ uint4 pack8(float4 a, float4 b) {
  union { unsigned short us[8]; uint4 q; } pk;
  pk.us[0] = f2bf(a.x); pk.us[1] = f2bf(a.y); pk.us[2] = f2bf(a.z); pk.us[3] = f2bf(a.w);
  pk.us[4] = f2bf(b.x); pk.us[5] = f2bf(b.y); pk.us[6] = f2bf(b.z); pk.us[7] = f2bf(b.w);
  return pk.q;
}

__device__ __forceinline__ float blk_sum(float v, float* red, int tid) {
  #pragma unroll
  for (int o = 32; o > 0; o >>= 1) v += __shfl_down(v, o, 64);
  __syncthreads();
  if ((tid & 63) == 0) red[tid >> 6] = v;
  __syncthreads();
  return red[0] + red[1] + red[2] + red[3];
}

__device__ __forceinline__ float blk_max(float v, float* red, int tid) {
  #pragma unroll
  for (int o = 32; o > 0; o >>= 1) v = fmaxf(v, __shfl_down(v, o, 64));
  __syncthreads();
  if ((tid & 63) == 0) red[tid >> 6] = v;
  __syncthreads();
  return fmaxf(fmaxf(red[0], red[1]), fmaxf(red[2], red[3]));
}

// ---------- embedding ----------
__global__ __launch_bounds__(256) void embed_kernel(
    const float* __restrict__ tok, const float* __restrict__ pos,
    const int* __restrict__ ids, float* __restrict__ X)
{
  int idx = blockIdx.x * 256 + threadIdx.x;     // < 8192*768 exactly
  int row = idx / DIMM, d = idx % DIMM;
  int l = row & (LL - 1);
  X[idx] = tok[(size_t)ids[row] * DIMM + d] + pos[(size_t)l * DIMM + d];
}

// ---------- layernorm (f32 in -> f32 out) ----------
__global__ __launch_bounds__(256) void ln_kernel(
    const float* __restrict__ X, const float* __restrict__ w,
    const float* __restrict__ b, float* __restrict__ O)
{
  __shared__ float red[8];
  int row = blockIdx.x, tid = threadIdx.x;
  const float* x = X + (size_t)row * DIMM;
  float v0 = x[tid], v1 = x[tid + 256], v2 = x[tid + 512];
  float mean = blk_sum(v0 + v1 + v2, red, tid) * (1.f / 768.f);
  float d0 = v0 - mean, d1 = v1 - mean, d2 = v2 - mean;
  float var = blk_sum(d0*d0 + d1*d1 + d2*d2, red, tid) * (1.f / 768.f);
  float rs = rsqrtf(var + 1e-5f);
  float* o = O + (size_t)row * DIMM;
  o[tid]       = d0 * rs * w[tid]       + b[tid];
  o[tid + 256] = d1 * rs * w[tid + 256] + b[tid + 256];
  o[tid + 512] = d2 * rs * w[tid + 512] + b[tid + 512];
}

// ---------- bf16 MFMA GEMM:  C[M,N] (+)= A[M,K] @ W[N,K]^T   (f32 io, inline bf16) ----------
// EPI 0: C = acc ; EPI 1: C += acc (residual)
template<int EPI>
__global__ __launch_bounds__(256) void gemm_kernel(
    const float* __restrict__ A, const float* __restrict__ W,
    float* __restrict__ C, int Nreal, int K, int lda, int ldw, int ldc)
{
  __shared__ unsigned short As[128][40];   // pad 40: conflict-free b128 reads
  __shared__ unsigned short Bs[128][40];
  const int tid = threadIdx.x;
  const int wave = tid >> 6, lane = tid & 63;
  const int wr = wave >> 1, wc = wave & 1;
  const int l15 = lane & 15, l4 = lane >> 4;
  const int bm = blockIdx.x * 128, bn = blockIdx.y * 128;
  f32x4 acc[4][4] = {};

  const int r0 = tid >> 2;            // 0..63
  const int c0 = (tid & 3) * 8;       // 0,8,16,24

  for (int k0 = 0; k0 < K; k0 += 32) {
    __syncthreads();
    #pragma unroll
    for (int i = 0; i < 2; i++) {
      int r = r0 + i * 64;
      { // A tile
        const float* src = A + (size_t)(bm + r) * lda + k0 + c0;
        float4 f0 = *(const float4*)src;
        float4 f1 = *(const float4*)(src + 4);
        *(uint4*)&As[r][c0] = pack8(f0, f1);
      }
      { // W tile (guard N)
        int wrow = bn + r;
        float4 f0 = {0,0,0,0}, f1 = {0,0,0,0};
        if (wrow < Nreal) {
          const float* src = W + (size_t)wrow * ldw + k0 + c0;
          f0 = *(const float4*)src;
          f1 = *(const float4*)(src + 4);
        }
        *(uint4*)&Bs[r][c0] = pack8(f0, f1);
      }
    }
    __syncthreads();
    s16x8 af[4], bfr[4];
    #pragma unroll
    for (int mi = 0; mi < 4; mi++)
      af[mi] = *(const s16x8*)&As[wr*64 + mi*16 + l15][l4*8];
    #pragma unroll
    for (int ni = 0; ni < 4; ni++)
      bfr[ni] = *(const s16x8*)&Bs[wc*64 + ni*16 + l15][l4*8];
    #pragma unroll
    for (int mi = 0; mi < 4; mi++)
      #pragma unroll
      for (int ni = 0; ni < 4; ni++)
        asm volatile("v_mfma_f32_16x16x32_bf16 %0, %1, %2, %0"
                     : "+v"(acc[mi][ni]) : "v"(af[mi]), "v"(bfr[ni]));
  }
  // MFMA->VALU read hazard fence: DEPENDENT s_nop per accumulator so the
  // epilogue reads are provably ordered after the wait states.
  #pragma unroll
  for (int mi = 0; mi < 4; mi++)
    #pragma unroll
    for (int ni = 0; ni < 4; ni++)
      asm volatile("s_nop 7" : "+v"(acc[mi][ni]));
  const int row0 = bm + wr*64 + l4*4;
  const int colb = bn + wc*64 + l15;
  #pragma unroll
  for (int mi = 0; mi < 4; mi++) {
    #pragma unroll
    for (int ni = 0; ni < 4; ni++) {
      int col = colb + ni*16;
      if (col < Nreal) {
        #pragma unroll
        for (int r = 0; r < 4; r++) {
          size_t idx = (size_t)(row0 + mi*16 + r) * ldc + col;
          if (EPI == 0) C[idx] = acc[mi][ni][r];
          else          C[idx] += acc[mi][ni][r];
        }
      }
    }
  }
}

// ---------- causal depthwise conv (taps=4) + bias + silu ----------
__global__ __launch_bounds__(256) void conv_kernel(
    const float* __restrict__ ZX, const float* __restrict__ cw,
    const float* __restrict__ cb, float* __restrict__ XC)
{
  int idx = blockIdx.x * 256 + threadIdx.x;    // < 8192*1664 exactly
  int c = idx % CONVD, row = idx / CONVD;
  int l = row & (LL - 1);
  const float* z = ZX + (size_t)row * DINP + DINNER + c;
  const float* w = cw + c * 4;
  float a = cb[c] + z[0] * w[3];
  if (l >= 1) a += z[-DINP]     * w[2];
  if (l >= 2) a += z[-2*DINP]   * w[1];
  if (l >= 3) a += z[-3*DINP]   * w[0];
  XC[idx] = a / (1.f + expf(-a));              // silu
}

// ---------- f32-exact dt + dA (precision-critical: dA = exp(dt*A), |A| up to 16) ----------
__global__ __launch_bounds__(256) void dt_kernel(
    const float* __restrict__ XN, const float* __restrict__ Wip,
    const float* __restrict__ dtb, const float* __restrict__ alog,
    float* __restrict__ DT, float* __restrict__ DA)
{
  __shared__ float xr[768];
  int row = blockIdx.x, tid = threadIdx.x;
  const float* x = XN + (size_t)row * DIMM;
  xr[tid] = x[tid]; xr[tid+256] = x[tid+256]; xr[tid+512] = x[tid+512];
  __syncthreads();
  int h = tid >> 3, sl = tid & 7;
  if (h < NH) {
    const float* w = Wip + (size_t)(3200 + h) * DIMM;   // dt rows start at 2*DINNER+2*DST
    float s = 0.f;
    for (int j = sl; j < 768; j += 8) s += xr[j] * w[j];
    #pragma unroll
    for (int o = 4; o > 0; o >>= 1) s += __shfl_down(s, o, 8);
    if (sl == 0) {
      float v = s + dtb[h];
      float dt = (v > 20.f) ? v : log1pf(expf(v));
      float da = expf(dt * (-expf(alog[h])));
      DT[row * NH + h] = dt;
      DA[row * NH + h] = da;
    }
  }
}

// ---------- sequential SSM scan, one wave per (b,head); fused D-skip + z-gate ----------
__global__ __launch_bounds__(64) void scan_kernel(
    const float* __restrict__ XC, const float* __restrict__ ZX,
    const float* __restrict__ DT, const float* __restrict__ DA,
    const float* __restrict__ Dp, float* __restrict__ Y)
{
  int b = blockIdx.x / NH, hd = blockIdx.x % NH;
  int p = threadIdx.x;
  float h[64];
  #pragma unroll
  for (int n = 0; n < 64; n++) h[n] = 0.f;
  float dhp = Dp[hd];
  #pragma unroll 2
  for (int l = 0; l < LL; l++) {
    size_t row = (size_t)b * LL + l;
    const float* xc = XC + row * CONVD;
    float x  = xc[hd*64 + p];
    float zv = ZX[row * DINP + hd*64 + p];
    float dt = DT[row * NH + hd];
    float da = DA[row * NH + hd];
    float dtx = dt * x;
    float y = 0.f;
    const float4* B4 = (const float4*)(xc + DINNER);
    const float4* C4 = (const float4*)(xc + DINNER + DST);
    #pragma unroll
    for (int q = 0; q < 16; q++) {
      float4 Bv = B4[q], Cv = C4[q];
      h[4*q+0] = h[4*q+0]*da + dtx*Bv.x;  y += h[4*q+0]*Cv.x;
      h[4*q+1] = h[4*q+1]*da + dtx*Bv.y;  y += h[4*q+1]*Cv.y;
      h[4*q+2] = h[4*q+2]*da + dtx*Bv.z;  y += h[4*q+2]*Cv.z;
      h[4*q+3] = h[4*q+3]*da + dtx*Bv.w;  y += h[4*q+3]*Cv.w;
    }
    float o  = y + dhp * x;
    float sg = zv / (1.f + expf(-zv));    // silu(z)
    Y[row * DINNER + hd*64 + p] = o * sg;
  }
}

// ---------- gated RMSNorm (in-place, 1536) ----------
__global__ __launch_bounds__(256) void rms_kernel(
    float* __restrict__ Y, const float* __restrict__ w)
{
  __shared__ float red[8];
  int row = blockIdx.x, tid = threadIdx.x;
  float* y = Y + (size_t)row * DINNER;
  float v[6]; float sq = 0.f;
  #pragma unroll
  for (int i = 0; i < 6; i++) { v[i] = y[tid + i*256]; sq += v[i]*v[i]; }
  float ms = blk_sum(sq, red, tid) * (1.f / 1536.f);
  float rs = rsqrtf(ms + 1e-5f);
  #pragma unroll
  for (int i = 0; i < 6; i++) y[tid + i*256] = v[i] * rs * w[tid + i*256];
}

// ---------- loss ----------
__global__ void zero_kernel(float* __restrict__ a) { a[0] = 0.f; }

__global__ __launch_bounds__(256) void loss_kernel(
    const float* __restrict__ logits, const int* __restrict__ labels,
    float* __restrict__ acc)
{
  __shared__ float red[8];
  int i = blockIdx.x;                 // 0..8187
  int b = i / (LL - 1), l = i % (LL - 1);
  const float* lr = logits + ((size_t)b * LL + l) * VOC;
  int tid = threadIdx.x;
  float mx = -1e30f;
  for (int j = tid; j < VOC; j += 256) mx = fmaxf(mx, lr[j]);
  mx = blk_max(mx, red, tid);
  float se = 0.f;
  for (int j = tid; j < VOC; j += 256) se += expf(lr[j] - mx);
  se = blk_sum(se, red, tid);
  if (tid == 0) {
    int lab = labels[b * LL + l + 1];
    float lp = lr[lab] - mx - logf(se);
    atomicAdd(acc, -lp);
  }
}

__global__ void fin_kernel(float* __restrict__ out, const float* __restrict__ acc) {
  out[0] = acc[0] * (1.f / 8188.f);
}

// ---------- launch ----------
extern "C" void kernel_launch(void* const* d_in, const int* in_sizes, int n_in,
                              void* d_out, int out_size, void* d_ws, size_t ws_size,
                              hipStream_t stream)
{
  const float* tok  = (const float*)d_in[0];
  const float* pos  = (const float*)d_in[1];
  const float* lnw  = (const float*)d_in[2];
  const float* lnb  = (const float*)d_in[3];
  const float* ipw  = (const float*)d_in[4];
  const float* cw   = (const float*)d_in[5];
  const float* cb   = (const float*)d_in[6];
  const float* dtb  = (const float*)d_in[7];
  const float* alog = (const float*)d_in[8];
  const float* dpar = (const float*)d_in[9];
  const float* nw   = (const float*)d_in[10];
  const float* opw  = (const float*)d_in[11];
  const float* nfw  = (const float*)d_in[12];
  const float* nfb  = (const float*)d_in[13];
  const float* hw   = (const float*)d_in[14];
  const int*   ids  = (const int*)d_in[15];
  const int*   labs = (const int*)d_in[16];
  float* out = (float*)d_out;

  char* ws = (char*)d_ws;
  float* X   = (float*)(ws);                         //  8192x768  f32
  float* XN  = (float*)(ws + 25165824ull);           //  8192x768  f32
  float* ZX  = (float*)(ws + 50331648ull);           //  8192x3224 f32
  float* XC  = (float*)(ws + 155975680ull);          //  8192x1664 f32
  float* DTv = (float*)(ws + 210501632ull);          //  8192x24
  float* DAv = (float*)(ws + 211288064ull);          //  8192x24
  float* Y   = (float*)(ws + 212074496ull);          //  8192x1536 f32
  float* ACC = (float*)(ws + 262406144ull);          //  1

  embed_kernel<<<ROWS*DIMM/256, 256, 0, stream>>>(tok, pos, ids, X);

  for (int l = 0; l < NLAYER; l++) {
    ln_kernel<<<ROWS, 256, 0, stream>>>(X, lnw + l*DIMM, lnb + l*DIMM, XN);

    dim3 g1(64, 26);   // N=3224 -> 26 tiles (guarded)
    gemm_kernel<0><<<g1, 256, 0, stream>>>(XN, ipw + (size_t)l*DINP*DIMM, ZX,
                                           DINP, DIMM, DIMM, DIMM, DINP);

    conv_kernel<<<ROWS*CONVD/256, 256, 0, stream>>>(ZX, cw + l*CONVD*4, cb + l*CONVD, XC);

    dt_kernel<<<ROWS, 256, 0, stream>>>(XN, ipw + (size_t)l*DINP*DIMM,
                                        dtb + l*NH, alog + l*NH, DTv, DAv);

    scan_kernel<<<NB*NH, 64, 0, stream>>>(XC, ZX, DTv, DAv, dpar + l*NH, Y);

    rms_kernel<<<ROWS, 256, 0, stream>>>(Y, nw + l*DINNER);

    dim3 g2(64, 6);
    gemm_kernel<1><<<g2, 256, 0, stream>>>(Y, opw + (size_t)l*DIMM*DINNER, X,
                                           DIMM, DINNER, DINNER, DINNER, DIMM);
  }

  ln_kernel<<<ROWS, 256, 0, stream>>>(X, nfw, nfb, XN);
  dim3 g3(64, 16);
  gemm_kernel<0><<<g3, 256, 0, stream>>>(XN, hw, out + 1, VOC, DIMM, DIMM, DIMM, VOC);

  zero_kernel<<<1, 1, 0, stream>>>(ACC);
  loss_kernel<<<NB*(LL-1), 256, 0, stream>>>(out + 1, labs, ACC);
  fin_kernel<<<1, 1, 0, stream>>>(out, ACC);
}

// Round 3
// 6022.044 us; speedup vs baseline: 4.6415x; 4.6415x over previous
//
#include <hip/hip_runtime.h>
#include <hip/hip_bf16.h>
#include <stdint.h>

#define DIMM   768
#define NLAYER 12
#define DST    64
#define DINNER 1536
#define NH     24
#define CONVD  1664
#define DINP   3224
#define NB     4
#define LL     2048
#define ROWS   (NB*LL)      // 8192
#define VOC    2048
#define Q      128          // SSD chunk length
#define NCH    (LL/Q)       // 16

typedef float f32x4 __attribute__((ext_vector_type(4)));
typedef short s16x8 __attribute__((ext_vector_type(8)));

#define MFMA(acc, a, b) asm volatile("v_mfma_f32_16x16x32_bf16 %0, %1, %2, %0" : "+v"(acc) : "v"(a), "v"(b))
#define FENCE4(v) asm volatile("s_nop 7" : "+v"(v))

// ---------- helpers ----------
__device__ __forceinline__ unsigned short f2bf(float f) {
  unsigned int u = __float_as_uint(f);
  u = (u + 0x7fffu + ((u >> 16) & 1u)) >> 16;   // RNE
  return (unsigned short)u;
}
__device__ __forceinline__ float bf2f(unsigned short u) {
  return __uint_as_float(((unsigned int)u) << 16);
}

__device__ __forceinline__ uint4 pack8(float4 a, float4 b) {
  union { unsigned short us[8]; uint4 q; } pk;
  pk.us[0] = f2bf(a.x); pk.us[1] = f2bf(a.y); pk.us[2] = f2bf(a.z); pk.us[3] = f2bf(a.w);
  pk.us[4] = f2bf(b.x); pk.us[5] = f2bf(b.y); pk.us[6] = f2bf(b.z); pk.us[7] = f2bf(b.w);
  return pk.q;
}

__device__ __forceinline__ float blk_sum(float v, float* red, int tid) {
  #pragma unroll
  for (int o = 32; o > 0; o >>= 1) v += __shfl_down(v, o, 64);
  __syncthreads();
  if ((tid & 63) == 0) red[tid >> 6] = v;
  __syncthreads();
  return red[0] + red[1] + red[2] + red[3];
}

__device__ __forceinline__ float blk_max(float v, float* red, int tid) {
  #pragma unroll
  for (int o = 32; o > 0; o >>= 1) v = fmaxf(v, __shfl_down(v, o, 64));
  __syncthreads();
  if ((tid & 63) == 0) red[tid >> 6] = v;
  __syncthreads();
  return fmaxf(fmaxf(red[0], red[1]), fmaxf(red[2], red[3]));
}

// ---------- embedding ----------
__global__ __launch_bounds__(256) void embed_kernel(
    const float* __restrict__ tok, const float* __restrict__ pos,
    const int* __restrict__ ids, float* __restrict__ X)
{
  int idx = blockIdx.x * 256 + threadIdx.x;
  int row = idx / DIMM, d = idx % DIMM;
  int l = row & (LL - 1);
  X[idx] = tok[(size_t)ids[row] * DIMM + d] + pos[(size_t)l * DIMM + d];
}

// ---------- layernorm ----------
__global__ __launch_bounds__(256) void ln_kernel(
    const float* __restrict__ X, const float* __restrict__ w,
    const float* __restrict__ b, float* __restrict__ O)
{
  __shared__ float red[8];
  int row = blockIdx.x, tid = threadIdx.x;
  const float* x = X + (size_t)row * DIMM;
  float v0 = x[tid], v1 = x[tid + 256], v2 = x[tid + 512];
  float mean = blk_sum(v0 + v1 + v2, red, tid) * (1.f / 768.f);
  float d0 = v0 - mean, d1 = v1 - mean, d2 = v2 - mean;
  float var = blk_sum(d0*d0 + d1*d1 + d2*d2, red, tid) * (1.f / 768.f);
  float rs = rsqrtf(var + 1e-5f);
  float* o = O + (size_t)row * DIMM;
  o[tid]       = d0 * rs * w[tid]       + b[tid];
  o[tid + 256] = d1 * rs * w[tid + 256] + b[tid + 256];
  o[tid + 512] = d2 * rs * w[tid + 512] + b[tid + 512];
}

// ---------- bf16 MFMA GEMM:  C[M,N] (+)= A[M,K] @ W[N,K]^T ----------
template<int EPI>
__global__ __launch_bounds__(256) void gemm_kernel(
    const float* __restrict__ A, const float* __restrict__ W,
    float* __restrict__ C, int Nreal, int K, int lda, int ldw, int ldc)
{
  __shared__ unsigned short As[128][40];
  __shared__ unsigned short Bs[128][40];
  const int tid = threadIdx.x;
  const int wave = tid >> 6, lane = tid & 63;
  const int wr = wave >> 1, wc = wave & 1;
  const int l15 = lane & 15, l4 = lane >> 4;
  const int bm = blockIdx.x * 128, bn = blockIdx.y * 128;
  f32x4 acc[4][4] = {};

  const int r0 = tid >> 2;
  const int c0 = (tid & 3) * 8;

  for (int k0 = 0; k0 < K; k0 += 32) {
    __syncthreads();
    #pragma unroll
    for (int i = 0; i < 2; i++) {
      int r = r0 + i * 64;
      {
        const float* src = A + (size_t)(bm + r) * lda + k0 + c0;
        float4 f0 = *(const float4*)src;
        float4 f1 = *(const float4*)(src + 4);
        *(uint4*)&As[r][c0] = pack8(f0, f1);
      }
      {
        int wrow = bn + r;
        float4 f0 = {0,0,0,0}, f1 = {0,0,0,0};
        if (wrow < Nreal) {
          const float* src = W + (size_t)wrow * ldw + k0 + c0;
          f0 = *(const float4*)src;
          f1 = *(const float4*)(src + 4);
        }
        *(uint4*)&Bs[r][c0] = pack8(f0, f1);
      }
    }
    __syncthreads();
    s16x8 af[4], bfr[4];
    #pragma unroll
    for (int mi = 0; mi < 4; mi++)
      af[mi] = *(const s16x8*)&As[wr*64 + mi*16 + l15][l4*8];
    #pragma unroll
    for (int ni = 0; ni < 4; ni++)
      bfr[ni] = *(const s16x8*)&Bs[wc*64 + ni*16 + l15][l4*8];
    #pragma unroll
    for (int mi = 0; mi < 4; mi++)
      #pragma unroll
      for (int ni = 0; ni < 4; ni++)
        MFMA(acc[mi][ni], af[mi], bfr[ni]);
  }
  #pragma unroll
  for (int mi = 0; mi < 4; mi++)
    #pragma unroll
    for (int ni = 0; ni < 4; ni++)
      FENCE4(acc[mi][ni]);
  const int row0 = bm + wr*64 + l4*4;
  const int colb = bn + wc*64 + l15;
  #pragma unroll
  for (int mi = 0; mi < 4; mi++) {
    #pragma unroll
    for (int ni = 0; ni < 4; ni++) {
      int col = colb + ni*16;
      if (col < Nreal) {
        #pragma unroll
        for (int r = 0; r < 4; r++) {
          size_t idx = (size_t)(row0 + mi*16 + r) * ldc + col;
          if (EPI == 0) C[idx] = acc[mi][ni][r];
          else          C[idx] += acc[mi][ni][r];
        }
      }
    }
  }
}

// ---------- causal depthwise conv (taps=4) + bias + silu ----------
__global__ __launch_bounds__(256) void conv_kernel(
    const float* __restrict__ ZX, const float* __restrict__ cw,
    const float* __restrict__ cb, float* __restrict__ XC)
{
  int idx = blockIdx.x * 256 + threadIdx.x;
  int c = idx % CONVD, row = idx / CONVD;
  int l = row & (LL - 1);
  const float* z = ZX + (size_t)row * DINP + DINNER + c;
  const float* w = cw + c * 4;
  float a = cb[c] + z[0] * w[3];
  if (l >= 1) a += z[-DINP]     * w[2];
  if (l >= 2) a += z[-2*DINP]   * w[1];
  if (l >= 3) a += z[-3*DINP]   * w[0];
  XC[idx] = a / (1.f + expf(-a));
}

// ---------- f32-exact dt + log-decay ----------
__global__ __launch_bounds__(256) void dt_kernel(
    const float* __restrict__ XN, const float* __restrict__ Wip,
    const float* __restrict__ dtb, const float* __restrict__ alog,
    float* __restrict__ DT, float* __restrict__ LDA)
{
  __shared__ float xr[768];
  int row = blockIdx.x, tid = threadIdx.x;
  const float* x = XN + (size_t)row * DIMM;
  xr[tid] = x[tid]; xr[tid+256] = x[tid+256]; xr[tid+512] = x[tid+512];
  __syncthreads();
  int h = tid >> 3, sl = tid & 7;
  if (h < NH) {
    const float* w = Wip + (size_t)(3200 + h) * DIMM;
    float s = 0.f;
    for (int j = sl; j < 768; j += 8) s += xr[j] * w[j];
    #pragma unroll
    for (int o = 4; o > 0; o >>= 1) s += __shfl_down(s, o, 8);
    if (sl == 0) {
      float v = s + dtb[h];
      float dt = (v > 20.f) ? v : log1pf(expf(v));
      DT[row * NH + h]  = dt;
      LDA[row * NH + h] = dt * (-expf(alog[h]));   // log of per-step decay (<=0)
    }
  }
}

// ---------- S1: per-chunk state  Hc[p][n] = sum_s x_s[p]*wgt_s*B_s[n] ----------
// wgt_s = exp(cum[Q-1]-cum[s])*dt_s ; grid (NB*NCH, NH), 256 thr
__global__ __launch_bounds__(256) void chunkstate_kernel(
    const float* __restrict__ XC_, const float* __restrict__ DT_,
    const float* __restrict__ LDA_, float* __restrict__ HC_)
{
  __shared__ unsigned short XT[64*136];   // XT[p][s] = bf16(x*wgt), stride 136
  __shared__ unsigned short BT[64*136];   // BT[n][s] = bf16(B)
  __shared__ float cum_sh[Q], wgt_sh[Q];
  __shared__ float carry;
  const int tid = threadIdx.x;
  const int b = blockIdx.x >> 4, c = blockIdx.x & 15, h = blockIdx.y;
  const size_t row0 = (size_t)b*LL + c*Q;

  // prefix over 128 log-decays (threads 0..127 = waves 0,1)
  float v = 0.f, dtv = 0.f;
  if (tid < Q) {
    v   = LDA_[(row0 + tid)*NH + h];
    dtv = DT_[(row0 + tid)*NH + h];
    #pragma unroll
    for (int off = 1; off < 64; off <<= 1) {
      float u = __shfl_up(v, off, 64);
      if ((tid & 63) >= off) v += u;
    }
  }
  if (tid == 63) carry = v;
  __syncthreads();
  if (tid >= 64 && tid < Q) v += carry;
  if (tid < Q) cum_sh[tid] = v;
  __syncthreads();
  if (tid < Q) wgt_sh[tid] = __expf(cum_sh[Q-1] - v) * dtv;
  __syncthreads();

  // stage transposed tiles
  const int p  = tid & 63;
  const int s0 = (tid >> 6) * 2;
  const float* xb = XC_ + row0 * CONVD;
  #pragma unroll
  for (int i = 0; i < 16; i++) {
    int s = s0 + i*8;
    float x0 = xb[(size_t)s*CONVD     + h*64 + p] * wgt_sh[s];
    float x1 = xb[(size_t)(s+1)*CONVD + h*64 + p] * wgt_sh[s+1];
    *(unsigned int*)&XT[p*136 + s] = (unsigned int)f2bf(x0) | ((unsigned int)f2bf(x1) << 16);
    float b0 = xb[(size_t)s*CONVD     + DINNER + p];
    float b1 = xb[(size_t)(s+1)*CONVD + DINNER + p];
    *(unsigned int*)&BT[p*136 + s] = (unsigned int)f2bf(b0) | ((unsigned int)f2bf(b1) << 16);
  }
  __syncthreads();

  // MFMA: [64p x 64n], K=128 over s ; waves 2x2
  const int wave = tid >> 6, lane = tid & 63, l15 = lane & 15, l4 = lane >> 4;
  const int wr = wave >> 1, wc = wave & 1;
  f32x4 acc[2][2] = {};
  #pragma unroll
  for (int ks = 0; ks < 4; ks++) {
    int kof = ks*32 + l4*8;
    s16x8 a0 = *(const s16x8*)&XT[(wr*32      + l15)*136 + kof];
    s16x8 a1 = *(const s16x8*)&XT[(wr*32 + 16 + l15)*136 + kof];
    s16x8 b0 = *(const s16x8*)&BT[(wc*32      + l15)*136 + kof];
    s16x8 b1 = *(const s16x8*)&BT[(wc*32 + 16 + l15)*136 + kof];
    MFMA(acc[0][0], a0, b0); MFMA(acc[0][1], a0, b1);
    MFMA(acc[1][0], a1, b0); MFMA(acc[1][1], a1, b1);
  }
  #pragma unroll
  for (int mi = 0; mi < 2; mi++)
    #pragma unroll
    for (int ni = 0; ni < 2; ni++)
      FENCE4(acc[mi][ni]);
  size_t base = (((size_t)(b*NH + h))*NCH + c)*4096;
  #pragma unroll
  for (int mi = 0; mi < 2; mi++)
    #pragma unroll
    for (int ni = 0; ni < 2; ni++)
      #pragma unroll
      for (int r = 0; r < 4; r++)
        HC_[base + (size_t)(wr*32 + mi*16 + l4*4 + r)*64 + wc*32 + ni*16 + l15] = acc[mi][ni][r];
}

// ---------- S2: inter-chunk recurrence (16 steps, 96 blocks) ----------
__global__ __launch_bounds__(256) void scan2_kernel(
    const float* __restrict__ HC_, float* __restrict__ HIN_,
    const float* __restrict__ LDA_)
{
  __shared__ float dec[NCH];
  int bh = blockIdx.x, b = bh / NH, h = bh % NH;
  int t = threadIdx.x;
  // chunk decay totals: thread t covers rows [8t, 8t+8) -> chunk t/16
  float part = 0.f;
  #pragma unroll
  for (int i = 0; i < 8; i++) part += LDA_[((size_t)b*LL + t*8 + i)*NH + h];
  #pragma unroll
  for (int off = 1; off < 16; off <<= 1) part += __shfl_xor(part, off, 16);
  if ((t & 15) == 0) dec[t >> 4] = __expf(part);
  __syncthreads();
  float st[16];
  #pragma unroll
  for (int i = 0; i < 16; i++) st[i] = 0.f;
  for (int c = 0; c < NCH; c++) {
    float d = dec[c];
    size_t base = ((size_t)bh*NCH + c)*4096;
    #pragma unroll
    for (int i = 0; i < 16; i++) {
      int idx = i*256 + t;
      HIN_[base + idx] = st[i];
      st[i] = st[i]*d + HC_[base + idx];
    }
  }
}

// ---------- S3: Y = (M@X)+exp(cum)*(C@Hin^T)+D*x, gated ----------
// grid (NB*NCH, NH), 256 thr
__global__ __launch_bounds__(256) void ydec_kernel(
    const float* __restrict__ XC_, const float* __restrict__ ZX_,
    const float* __restrict__ DT_, const float* __restrict__ LDA_,
    const float* __restrict__ HIN_, const float* __restrict__ Dp_,
    float* __restrict__ Y_)
{
  __shared__ unsigned short POOL[128*72*2];   // Cs[128][72] | Bs[128][72]; reused as M[128][136]
  __shared__ unsigned short Hs[64*72];        // Hin[p][n] bf16
  __shared__ unsigned short XTs[64*136];      // x^T[p][s] bf16
  __shared__ float cum_sh[Q], dt_sh[Q];
  __shared__ float carry;
  unsigned short* Cs = POOL;
  unsigned short* Bs = POOL + 128*72;
  unsigned short* Ms = POOL;

  const int tid = threadIdx.x;
  const int b = blockIdx.x >> 4, c = blockIdx.x & 15, h = blockIdx.y;
  const size_t row0 = (size_t)b*LL + c*Q;

  // prefix cum + dt
  float v = 0.f, dtv = 0.f;
  if (tid < Q) {
    v   = LDA_[(row0 + tid)*NH + h];
    dtv = DT_[(row0 + tid)*NH + h];
    #pragma unroll
    for (int off = 1; off < 64; off <<= 1) {
      float u = __shfl_up(v, off, 64);
      if ((tid & 63) >= off) v += u;
    }
  }
  if (tid == 63) carry = v;
  __syncthreads();
  if (tid >= 64 && tid < Q) v += carry;
  if (tid < Q) { cum_sh[tid] = v; dt_sh[tid] = dtv; }

  // stage C, B, XT, H
  const int p  = tid & 63;
  const int s0 = (tid >> 6) * 2;
  const float* xb = XC_ + row0 * CONVD;
  #pragma unroll
  for (int i = 0; i < 16; i++) {
    int s = s0 + i*8;
    Cs[(size_t)s*72 + p]     = f2bf(xb[(size_t)s*CONVD     + DINNER + DST + p]);
    Cs[(size_t)(s+1)*72 + p] = f2bf(xb[(size_t)(s+1)*CONVD + DINNER + DST + p]);
    Bs[(size_t)s*72 + p]     = f2bf(xb[(size_t)s*CONVD     + DINNER + p]);
    Bs[(size_t)(s+1)*72 + p] = f2bf(xb[(size_t)(s+1)*CONVD + DINNER + p]);
    float x0 = xb[(size_t)s*CONVD     + h*64 + p];
    float x1 = xb[(size_t)(s+1)*CONVD + h*64 + p];
    *(unsigned int*)&XTs[p*136 + s] = (unsigned int)f2bf(x0) | ((unsigned int)f2bf(x1) << 16);
  }
  {
    size_t hb = (((size_t)(b*NH + h))*NCH + c)*4096;
    #pragma unroll
    for (int i = 0; i < 16; i++) {
      int idx = i*256 + tid;
      Hs[(idx >> 6)*72 + (idx & 63)] = f2bf(HIN_[hb + idx]);
    }
  }
  __syncthreads();

  const int wv = tid >> 6, lane = tid & 63, l15 = lane & 15, l4 = lane >> 4;
  const int tb = wv * 32;

  // phase 2: G = C@B^T (lower tiles only) and Yinter = C@H^T
  f32x4 g[2][8] = {};
  f32x4 yacc[2][4] = {};
  #pragma unroll
  for (int ks = 0; ks < 2; ks++) {
    int kof = ks*32 + l4*8;
    s16x8 a0 = *(const s16x8*)&Cs[(size_t)(tb      + l15)*72 + kof];
    s16x8 a1 = *(const s16x8*)&Cs[(size_t)(tb + 16 + l15)*72 + kof];
    #pragma unroll
    for (int ni = 0; ni < 8; ni++) {
      if (ni <= 2*wv + 1) {
        s16x8 bfr = *(const s16x8*)&Bs[(size_t)(ni*16 + l15)*72 + kof];
        if (ni <= 2*wv) MFMA(g[0][ni], a0, bfr);
        MFMA(g[1][ni], a1, bfr);
      }
    }
    #pragma unroll
    for (int ni2 = 0; ni2 < 4; ni2++) {
      s16x8 hf = *(const s16x8*)&Hs[(size_t)(ni2*16 + l15)*72 + kof];
      MFMA(yacc[0][ni2], a0, hf);
      MFMA(yacc[1][ni2], a1, hf);
    }
  }
  __syncthreads();   // all waves done reading Cs/Bs before M overwrites

  // phase 3: M[t][s] = g * exp(cum[t]-cum[s]) * dt[s]  (s<=t else 0)
  #pragma unroll
  for (int mi = 0; mi < 2; mi++) {
    #pragma unroll
    for (int ni = 0; ni < 8; ni++) {
      FENCE4(g[mi][ni]);
      int t0 = tb + mi*16 + l4*4;
      int s  = ni*16 + l15;
      float ds = dt_sh[s], cs = cum_sh[s];
      #pragma unroll
      for (int r = 0; r < 4; r++) {
        int tt = t0 + r;
        float val = (s <= tt) ? g[mi][ni][r] * __expf(cum_sh[tt] - cs) * ds : 0.f;
        Ms[(size_t)tt*136 + s] = f2bf(val);
      }
    }
  }

  // scale Yinter by exp(cum[t])
  float er[2][4];
  #pragma unroll
  for (int mi = 0; mi < 2; mi++)
    #pragma unroll
    for (int r = 0; r < 4; r++)
      er[mi][r] = __expf(cum_sh[tb + mi*16 + l4*4 + r]);
  #pragma unroll
  for (int mi = 0; mi < 2; mi++)
    #pragma unroll
    for (int ni2 = 0; ni2 < 4; ni2++) {
      FENCE4(yacc[mi][ni2]);
      #pragma unroll
      for (int r = 0; r < 4; r++) yacc[mi][ni2][r] *= er[mi][r];
      FENCE4(yacc[mi][ni2]);   // VALU->MFMA srcC hazard
    }

  // phase 5: Yintra += M @ X^T  (own rows only; same-wave LDS RAW)
  #pragma unroll
  for (int ks = 0; ks < 4; ks++) {
    int kof = ks*32 + l4*8;
    s16x8 a0 = *(const s16x8*)&Ms[(size_t)(tb      + l15)*136 + kof];
    s16x8 a1 = *(const s16x8*)&Ms[(size_t)(tb + 16 + l15)*136 + kof];
    #pragma unroll
    for (int ni2 = 0; ni2 < 4; ni2++) {
      s16x8 xf = *(const s16x8*)&XTs[(size_t)(ni2*16 + l15)*136 + kof];
      MFMA(yacc[0][ni2], a0, xf);
      MFMA(yacc[1][ni2], a1, xf);
    }
  }
  #pragma unroll
  for (int mi = 0; mi < 2; mi++)
    #pragma unroll
    for (int ni2 = 0; ni2 < 4; ni2++)
      FENCE4(yacc[mi][ni2]);

  // epilogue: + D*x, gate with silu(z), store
  float Dv = Dp_[h];
  #pragma unroll
  for (int mi = 0; mi < 2; mi++) {
    #pragma unroll
    for (int ni2 = 0; ni2 < 4; ni2++) {
      #pragma unroll
      for (int r = 0; r < 4; r++) {
        int t = tb + mi*16 + l4*4 + r;
        int pc = ni2*16 + l15;
        float xv = bf2f(XTs[pc*136 + t]);
        float yv = yacc[mi][ni2][r] + Dv * xv;
        size_t row = row0 + t;
        float zv = ZX_[row*DINP + h*64 + pc];
        Y_[row*DINNER + h*64 + pc] = yv * (zv / (1.f + expf(-zv)));
      }
    }
  }
}

// ---------- gated RMSNorm ----------
__global__ __launch_bounds__(256) void rms_kernel(
    float* __restrict__ Y, const float* __restrict__ w)
{
  __shared__ float red[8];
  int row = blockIdx.x, tid = threadIdx.x;
  float* y = Y + (size_t)row * DINNER;
  float v[6]; float sq = 0.f;
  #pragma unroll
  for (int i = 0; i < 6; i++) { v[i] = y[tid + i*256]; sq += v[i]*v[i]; }
  float ms = blk_sum(sq, red, tid) * (1.f / 1536.f);
  float rs = rsqrtf(ms + 1e-5f);
  #pragma unroll
  for (int i = 0; i < 6; i++) y[tid + i*256] = v[i] * rs * w[tid + i*256];
}

// ---------- loss ----------
__global__ void zero_kernel(float* __restrict__ a) { a[0] = 0.f; }

__global__ __launch_bounds__(256) void loss_kernel(
    const float* __restrict__ logits, const int* __restrict__ labels,
    float* __restrict__ acc)
{
  __shared__ float red[8];
  int i = blockIdx.x;
  int b = i / (LL - 1), l = i % (LL - 1);
  const float* lr = logits + ((size_t)b * LL + l) * VOC;
  int tid = threadIdx.x;
  float mx = -1e30f;
  for (int j = tid; j < VOC; j += 256) mx = fmaxf(mx, lr[j]);
  mx = blk_max(mx, red, tid);
  float se = 0.f;
  for (int j = tid; j < VOC; j += 256) se += expf(lr[j] - mx);
  se = blk_sum(se, red, tid);
  if (tid == 0) {
    int lab = labels[b * LL + l + 1];
    float lp = lr[lab] - mx - logf(se);
    atomicAdd(acc, -lp);
  }
}

__global__ void fin_kernel(float* __restrict__ out, const float* __restrict__ acc) {
  out[0] = acc[0] * (1.f / 8188.f);
}

// ---------- launch ----------
extern "C" void kernel_launch(void* const* d_in, const int* in_sizes, int n_in,
                              void* d_out, int out_size, void* d_ws, size_t ws_size,
                              hipStream_t stream)
{
  const float* tok  = (const float*)d_in[0];
  const float* pos  = (const float*)d_in[1];
  const float* lnw  = (const float*)d_in[2];
  const float* lnb  = (const float*)d_in[3];
  const float* ipw  = (const float*)d_in[4];
  const float* cw   = (const float*)d_in[5];
  const float* cb   = (const float*)d_in[6];
  const float* dtb  = (const float*)d_in[7];
  const float* alog = (const float*)d_in[8];
  const float* dpar = (const float*)d_in[9];
  const float* nw   = (const float*)d_in[10];
  const float* opw  = (const float*)d_in[11];
  const float* nfw  = (const float*)d_in[12];
  const float* nfb  = (const float*)d_in[13];
  const float* hw   = (const float*)d_in[14];
  const int*   ids  = (const int*)d_in[15];
  const int*   labs = (const int*)d_in[16];
  float* out = (float*)d_out;

  char* ws = (char*)d_ws;
  float* X    = (float*)(ws);                         //  8192x768  f32
  float* XN   = (float*)(ws + 25165824ull);           //  8192x768  f32 (aliased by HC after dt_kernel)
  float* ZX   = (float*)(ws + 50331648ull);           //  8192x3224 f32
  float* XC   = (float*)(ws + 155975680ull);          //  8192x1664 f32
  float* DTv  = (float*)(ws + 210501632ull);          //  8192x24
  float* LDAv = (float*)(ws + 211288064ull);          //  8192x24 (log decay)
  float* Y    = (float*)(ws + 212074496ull);          //  8192x1536 f32
  float* ACC  = (float*)(ws + 262406144ull);          //  1
  float* HC   = XN;                                   //  96*16*4096 f32 = 25.16MB (alias)
  float* HIN  = out + 1 + 8388608;                    //  6.29M f32 in logits region (dead before head gemm)

  embed_kernel<<<ROWS*DIMM/256, 256, 0, stream>>>(tok, pos, ids, X);

  for (int l = 0; l < NLAYER; l++) {
    ln_kernel<<<ROWS, 256, 0, stream>>>(X, lnw + l*DIMM, lnb + l*DIMM, XN);

    dim3 g1(64, 26);
    gemm_kernel<0><<<g1, 256, 0, stream>>>(XN, ipw + (size_t)l*DINP*DIMM, ZX,
                                           DINP, DIMM, DIMM, DIMM, DINP);

    conv_kernel<<<ROWS*CONVD/256, 256, 0, stream>>>(ZX, cw + l*CONVD*4, cb + l*CONVD, XC);

    dt_kernel<<<ROWS, 256, 0, stream>>>(XN, ipw + (size_t)l*DINP*DIMM,
                                        dtb + l*NH, alog + l*NH, DTv, LDAv);

    dim3 gs(NB*NCH, NH);
    chunkstate_kernel<<<gs, 256, 0, stream>>>(XC, DTv, LDAv, HC);
    scan2_kernel<<<NB*NH, 256, 0, stream>>>(HC, HIN, LDAv);
    ydec_kernel<<<gs, 256, 0, stream>>>(XC, ZX, DTv, LDAv, HIN, dpar + l*NH, Y);

    rms_kernel<<<ROWS, 256, 0, stream>>>(Y, nw + l*DINNER);

    dim3 g2(64, 6);
    gemm_kernel<1><<<g2, 256, 0, stream>>>(Y, opw + (size_t)l*DIMM*DINNER, X,
                                           DIMM, DINNER, DINNER, DINNER, DIMM);
  }

  ln_kernel<<<ROWS, 256, 0, stream>>>(X, nfw, nfb, XN);
  dim3 g3(64, 16);
  gemm_kernel<0><<<g3, 256, 0, stream>>>(XN, hw, out + 1, VOC, DIMM, DIMM, DIMM, VOC);

  zero_kernel<<<1, 1, 0, stream>>>(ACC);
  loss_kernel<<<NB*(LL-1), 256, 0, stream>>>(out + 1, labs, ACC);
  fin_kernel<<<1, 1, 0, stream>>>(out, ACC);
}

// Round 4
// 4560.894 us; speedup vs baseline: 6.1284x; 1.3204x over previous
//
#include <hip/hip_runtime.h>
#include <hip/hip_bf16.h>
#include <stdint.h>

#define DIMM   768
#define NLAYER 12
#define DST    64
#define DINNER 1536
#define NH     24
#define CONVD  1664
#define DINP   3224
#define NB     4
#define LL     2048
#define ROWS   (NB*LL)      // 8192
#define VOC    2048
#define Q      128          // SSD chunk length
#define NCH    (LL/Q)       // 16

typedef float f32x4 __attribute__((ext_vector_type(4)));
typedef short s16x8 __attribute__((ext_vector_type(8)));

#define MFMA(acc, a, b) asm volatile("v_mfma_f32_16x16x32_bf16 %0, %1, %2, %0" : "+v"(acc) : "v"(a), "v"(b))
#define FENCE4(v) asm volatile("s_nop 7" : "+v"(v))
#define GLL16(g, l) __builtin_amdgcn_global_load_lds( \
    (const __attribute__((address_space(1))) uint32_t*)(g), \
    (__attribute__((address_space(3))) uint32_t*)(l), 16, 0, 0)

// ---------- helpers ----------
__device__ __forceinline__ unsigned short f2bf(float f) {
  unsigned int u = __float_as_uint(f);
  u = (u + 0x7fffu + ((u >> 16) & 1u)) >> 16;   // RNE
  return (unsigned short)u;
}
__device__ __forceinline__ float bf2f(unsigned short u) {
  return __uint_as_float(((unsigned int)u) << 16);
}

__device__ __forceinline__ uint4 pack8(float4 a, float4 b) {
  union { unsigned short us[8]; uint4 q; } pk;
  pk.us[0] = f2bf(a.x); pk.us[1] = f2bf(a.y); pk.us[2] = f2bf(a.z); pk.us[3] = f2bf(a.w);
  pk.us[4] = f2bf(b.x); pk.us[5] = f2bf(b.y); pk.us[6] = f2bf(b.z); pk.us[7] = f2bf(b.w);
  return pk.q;
}

__device__ __forceinline__ float blk_sum(float v, float* red, int tid) {
  #pragma unroll
  for (int o = 32; o > 0; o >>= 1) v += __shfl_down(v, o, 64);
  __syncthreads();
  if ((tid & 63) == 0) red[tid >> 6] = v;
  __syncthreads();
  return red[0] + red[1] + red[2] + red[3];
}

__device__ __forceinline__ float blk_max(float v, float* red, int tid) {
  #pragma unroll
  for (int o = 32; o > 0; o >>= 1) v = fmaxf(v, __shfl_down(v, o, 64));
  __syncthreads();
  if ((tid & 63) == 0) red[tid >> 6] = v;
  __syncthreads();
  return fmaxf(fmaxf(red[0], red[1]), fmaxf(red[2], red[3]));
}

// ---------- weight f32 -> bf16 (once per use; removes conversion from GEMM) ----------
__global__ __launch_bounds__(256) void cvt_kernel(
    const float* __restrict__ s, unsigned short* __restrict__ d, int n8)
{
  int i = blockIdx.x * 256 + threadIdx.x;
  if (i < n8) {
    float4 a = ((const float4*)s)[i*2];
    float4 b = ((const float4*)s)[i*2 + 1];
    ((uint4*)d)[i] = pack8(a, b);
  }
}

// ---------- embedding ----------
__global__ __launch_bounds__(256) void embed_kernel(
    const float* __restrict__ tok, const float* __restrict__ pos,
    const int* __restrict__ ids, float* __restrict__ X)
{
  int idx = blockIdx.x * 256 + threadIdx.x;
  int row = idx / DIMM, d = idx % DIMM;
  int l = row & (LL - 1);
  X[idx] = tok[(size_t)ids[row] * DIMM + d] + pos[(size_t)l * DIMM + d];
}

// ---------- layernorm: f32 out (for dt) + bf16 out (for GEMM A) ----------
__global__ __launch_bounds__(256) void ln_kernel(
    const float* __restrict__ X, const float* __restrict__ w,
    const float* __restrict__ b, float* __restrict__ O,
    unsigned short* __restrict__ Ob)
{
  __shared__ float red[8];
  int row = blockIdx.x, tid = threadIdx.x;
  const float* x = X + (size_t)row * DIMM;
  float v0 = x[tid], v1 = x[tid + 256], v2 = x[tid + 512];
  float mean = blk_sum(v0 + v1 + v2, red, tid) * (1.f / 768.f);
  float d0 = v0 - mean, d1 = v1 - mean, d2 = v2 - mean;
  float var = blk_sum(d0*d0 + d1*d1 + d2*d2, red, tid) * (1.f / 768.f);
  float rs = rsqrtf(var + 1e-5f);
  float* o = O + (size_t)row * DIMM;
  unsigned short* ob = Ob + (size_t)row * DIMM;
  float r0 = d0 * rs * w[tid]       + b[tid];
  float r1 = d1 * rs * w[tid + 256] + b[tid + 256];
  float r2 = d2 * rs * w[tid + 512] + b[tid + 512];
  o[tid] = r0; o[tid + 256] = r1; o[tid + 512] = r2;
  ob[tid] = f2bf(r0); ob[tid + 256] = f2bf(r1); ob[tid + 512] = f2bf(r2);
}

// ---------- bf16 MFMA GEMM (m97 structure): C[M,N] (+)= A[M,K] @ W[N,K]^T ----------
// bf16 inputs, global_load_lds staging, linear LDS, 2-barrier K-loop.
template<int EPI>
__global__ __launch_bounds__(256) void gemm_kernel(
    const unsigned short* __restrict__ A, const unsigned short* __restrict__ W,
    float* __restrict__ C, int Nreal, int K, int lda, int ldw, int ldc)
{
  __shared__ unsigned short As[128*32];
  __shared__ unsigned short Bs[128*32];
  const int tid = threadIdx.x;
  const int wave = tid >> 6, lane = tid & 63;
  const int wr = wave >> 1, wc = wave & 1;
  const int l15 = lane & 15, l4 = lane >> 4;
  const int bm = blockIdx.x * 128, bn = blockIdx.y * 128;
  f32x4 acc[4][4] = {};

  // staging: wave-chunk j covers rows [(wave*2+j)*16, +16), lane l -> row +l/4, col (l&3)*8
  const int srow = lane >> 2;
  const int scol = (lane & 3) * 8;
  const unsigned short* aptr[2];
  const unsigned short* wptr[2];
  unsigned short* alds[2];
  unsigned short* blds[2];
  #pragma unroll
  for (int j = 0; j < 2; j++) {
    int row = (wave*2 + j)*16 + srow;
    aptr[j] = A + (size_t)(bm + row) * lda + scol;
    int wrow = bn + row; if (wrow > Nreal - 1) wrow = Nreal - 1;   // clamp; masked at store
    wptr[j] = W + (size_t)wrow * ldw + scol;
    alds[j] = &As[(wave*2 + j) * 512];
    blds[j] = &Bs[(wave*2 + j) * 512];
  }

  for (int k0 = 0; k0 < K; k0 += 32) {
    __syncthreads();                       // previous iter's LDS reads done
    #pragma unroll
    for (int j = 0; j < 2; j++) {
      GLL16(aptr[j], alds[j]);
      GLL16(wptr[j], blds[j]);
      aptr[j] += 32; wptr[j] += 32;
    }
    __syncthreads();                       // drains vmcnt(0) before barrier
    s16x8 af[4], bfr[4];
    #pragma unroll
    for (int mi = 0; mi < 4; mi++)
      af[mi] = *(const s16x8*)&As[(wr*64 + mi*16 + l15)*32 + l4*8];
    #pragma unroll
    for (int ni = 0; ni < 4; ni++)
      bfr[ni] = *(const s16x8*)&Bs[(wc*64 + ni*16 + l15)*32 + l4*8];
    #pragma unroll
    for (int mi = 0; mi < 4; mi++)
      #pragma unroll
      for (int ni = 0; ni < 4; ni++)
        MFMA(acc[mi][ni], af[mi], bfr[ni]);
  }
  #pragma unroll
  for (int mi = 0; mi < 4; mi++)
    #pragma unroll
    for (int ni = 0; ni < 4; ni++)
      FENCE4(acc[mi][ni]);
  const int row0 = bm + wr*64 + l4*4;
  const int colb = bn + wc*64 + l15;
  #pragma unroll
  for (int mi = 0; mi < 4; mi++) {
    #pragma unroll
    for (int ni = 0; ni < 4; ni++) {
      int col = colb + ni*16;
      if (col < Nreal) {
        #pragma unroll
        for (int r = 0; r < 4; r++) {
          size_t idx = (size_t)(row0 + mi*16 + r) * ldc + col;
          if (EPI == 0) C[idx] = acc[mi][ni][r];
          else          C[idx] += acc[mi][ni][r];
        }
      }
    }
  }
}

// ---------- causal depthwise conv (taps=4) + bias + silu ----------
__global__ __launch_bounds__(256) void conv_kernel(
    const float* __restrict__ ZX, const float* __restrict__ cw,
    const float* __restrict__ cb, float* __restrict__ XC)
{
  int idx = blockIdx.x * 256 + threadIdx.x;
  int c = idx % CONVD, row = idx / CONVD;
  int l = row & (LL - 1);
  const float* z = ZX + (size_t)row * DINP + DINNER + c;
  const float* w = cw + c * 4;
  float a = cb[c] + z[0] * w[3];
  if (l >= 1) a += z[-DINP]     * w[2];
  if (l >= 2) a += z[-2*DINP]   * w[1];
  if (l >= 3) a += z[-3*DINP]   * w[0];
  XC[idx] = a / (1.f + expf(-a));
}

// ---------- f32-exact dt + log-decay ----------
__global__ __launch_bounds__(256) void dt_kernel(
    const float* __restrict__ XN, const float* __restrict__ Wip,
    const float* __restrict__ dtb, const float* __restrict__ alog,
    float* __restrict__ DT, float* __restrict__ LDA)
{
  __shared__ float xr[768];
  int row = blockIdx.x, tid = threadIdx.x;
  const float* x = XN + (size_t)row * DIMM;
  xr[tid] = x[tid]; xr[tid+256] = x[tid+256]; xr[tid+512] = x[tid+512];
  __syncthreads();
  int h = tid >> 3, sl = tid & 7;
  if (h < NH) {
    const float* w = Wip + (size_t)(3200 + h) * DIMM;
    float s = 0.f;
    for (int j = sl; j < 768; j += 8) s += xr[j] * w[j];
    #pragma unroll
    for (int o = 4; o > 0; o >>= 1) s += __shfl_down(s, o, 8);
    if (sl == 0) {
      float v = s + dtb[h];
      float dt = (v > 20.f) ? v : log1pf(expf(v));
      DT[row * NH + h]  = dt;
      LDA[row * NH + h] = dt * (-expf(alog[h]));
    }
  }
}

// ---------- S1: per-chunk state ----------
__global__ __launch_bounds__(256) void chunkstate_kernel(
    const float* __restrict__ XC_, const float* __restrict__ DT_,
    const float* __restrict__ LDA_, float* __restrict__ HC_)
{
  __shared__ unsigned short XT[64*136];
  __shared__ unsigned short BT[64*136];
  __shared__ float cum_sh[Q], wgt_sh[Q];
  __shared__ float carry;
  const int tid = threadIdx.x;
  const int b = blockIdx.x >> 4, c = blockIdx.x & 15, h = blockIdx.y;
  const size_t row0 = (size_t)b*LL + c*Q;

  float v = 0.f, dtv = 0.f;
  if (tid < Q) {
    v   = LDA_[(row0 + tid)*NH + h];
    dtv = DT_[(row0 + tid)*NH + h];
    #pragma unroll
    for (int off = 1; off < 64; off <<= 1) {
      float u = __shfl_up(v, off, 64);
      if ((tid & 63) >= off) v += u;
    }
  }
  if (tid == 63) carry = v;
  __syncthreads();
  if (tid >= 64 && tid < Q) v += carry;
  if (tid < Q) cum_sh[tid] = v;
  __syncthreads();
  if (tid < Q) wgt_sh[tid] = __expf(cum_sh[Q-1] - v) * dtv;
  __syncthreads();

  const int p  = tid & 63;
  const int s0 = (tid >> 6) * 2;
  const float* xb = XC_ + row0 * CONVD;
  #pragma unroll
  for (int i = 0; i < 16; i++) {
    int s = s0 + i*8;
    float x0 = xb[(size_t)s*CONVD     + h*64 + p] * wgt_sh[s];
    float x1 = xb[(size_t)(s+1)*CONVD + h*64 + p] * wgt_sh[s+1];
    *(unsigned int*)&XT[p*136 + s] = (unsigned int)f2bf(x0) | ((unsigned int)f2bf(x1) << 16);
    float b0 = xb[(size_t)s*CONVD     + DINNER + p];
    float b1 = xb[(size_t)(s+1)*CONVD + DINNER + p];
    *(unsigned int*)&BT[p*136 + s] = (unsigned int)f2bf(b0) | ((unsigned int)f2bf(b1) << 16);
  }
  __syncthreads();

  const int wave = tid >> 6, lane = tid & 63, l15 = lane & 15, l4 = lane >> 4;
  const int wr = wave >> 1, wc = wave & 1;
  f32x4 acc[2][2] = {};
  #pragma unroll
  for (int ks = 0; ks < 4; ks++) {
    int kof = ks*32 + l4*8;
    s16x8 a0 = *(const s16x8*)&XT[(wr*32      + l15)*136 + kof];
    s16x8 a1 = *(const s16x8*)&XT[(wr*32 + 16 + l15)*136 + kof];
    s16x8 b0 = *(const s16x8*)&BT[(wc*32      + l15)*136 + kof];
    s16x8 b1 = *(const s16x8*)&BT[(wc*32 + 16 + l15)*136 + kof];
    MFMA(acc[0][0], a0, b0); MFMA(acc[0][1], a0, b1);
    MFMA(acc[1][0], a1, b0); MFMA(acc[1][1], a1, b1);
  }
  #pragma unroll
  for (int mi = 0; mi < 2; mi++)
    #pragma unroll
    for (int ni = 0; ni < 2; ni++)
      FENCE4(acc[mi][ni]);
  size_t base = (((size_t)(b*NH + h))*NCH + c)*4096;
  #pragma unroll
  for (int mi = 0; mi < 2; mi++)
    #pragma unroll
    for (int ni = 0; ni < 2; ni++)
      #pragma unroll
      for (int r = 0; r < 4; r++)
        HC_[base + (size_t)(wr*32 + mi*16 + l4*4 + r)*64 + wc*32 + ni*16 + l15] = acc[mi][ni][r];
}

// ---------- S2: inter-chunk recurrence ----------
__global__ __launch_bounds__(256) void scan2_kernel(
    const float* __restrict__ HC_, float* __restrict__ HIN_,
    const float* __restrict__ LDA_)
{
  __shared__ float dec[NCH];
  int bh = blockIdx.x, b = bh / NH, h = bh % NH;
  int t = threadIdx.x;
  float part = 0.f;
  #pragma unroll
  for (int i = 0; i < 8; i++) part += LDA_[((size_t)b*LL + t*8 + i)*NH + h];
  #pragma unroll
  for (int off = 1; off < 16; off <<= 1) part += __shfl_xor(part, off, 16);
  if ((t & 15) == 0) dec[t >> 4] = __expf(part);
  __syncthreads();
  float st[16];
  #pragma unroll
  for (int i = 0; i < 16; i++) st[i] = 0.f;
  for (int c = 0; c < NCH; c++) {
    float d = dec[c];
    size_t base = ((size_t)bh*NCH + c)*4096;
    #pragma unroll
    for (int i = 0; i < 16; i++) {
      int idx = i*256 + t;
      HIN_[base + idx] = st[i];
      st[i] = st[i]*d + HC_[base + idx];
    }
  }
}

// ---------- S3: Y = (M@X)+exp(cum)*(C@Hin^T)+D*x, gated; bf16 out ----------
__global__ __launch_bounds__(256) void ydec_kernel(
    const float* __restrict__ XC_, const float* __restrict__ ZX_,
    const float* __restrict__ DT_, const float* __restrict__ LDA_,
    const float* __restrict__ HIN_, const float* __restrict__ Dp_,
    unsigned short* __restrict__ Y_)
{
  __shared__ unsigned short POOL[128*72*2];
  __shared__ unsigned short Hs[64*72];
  __shared__ unsigned short XTs[64*136];
  __shared__ float cum_sh[Q], dt_sh[Q];
  __shared__ float carry;
  unsigned short* Cs = POOL;
  unsigned short* Bs = POOL + 128*72;
  unsigned short* Ms = POOL;

  const int tid = threadIdx.x;
  const int b = blockIdx.x >> 4, c = blockIdx.x & 15, h = blockIdx.y;
  const size_t row0 = (size_t)b*LL + c*Q;

  float v = 0.f, dtv = 0.f;
  if (tid < Q) {
    v   = LDA_[(row0 + tid)*NH + h];
    dtv = DT_[(row0 + tid)*NH + h];
    #pragma unroll
    for (int off = 1; off < 64; off <<= 1) {
      float u = __shfl_up(v, off, 64);
      if ((tid & 63) >= off) v += u;
    }
  }
  if (tid == 63) carry = v;
  __syncthreads();
  if (tid >= 64 && tid < Q) v += carry;
  if (tid < Q) { cum_sh[tid] = v; dt_sh[tid] = dtv; }

  const int p  = tid & 63;
  const int s0 = (tid >> 6) * 2;
  const float* xb = XC_ + row0 * CONVD;
  #pragma unroll
  for (int i = 0; i < 16; i++) {
    int s = s0 + i*8;
    Cs[(size_t)s*72 + p]     = f2bf(xb[(size_t)s*CONVD     + DINNER + DST + p]);
    Cs[(size_t)(s+1)*72 + p] = f2bf(xb[(size_t)(s+1)*CONVD + DINNER + DST + p]);
    Bs[(size_t)s*72 + p]     = f2bf(xb[(size_t)s*CONVD     + DINNER + p]);
    Bs[(size_t)(s+1)*72 + p] = f2bf(xb[(size_t)(s+1)*CONVD + DINNER + p]);
    float x0 = xb[(size_t)s*CONVD     + h*64 + p];
    float x1 = xb[(size_t)(s+1)*CONVD + h*64 + p];
    *(unsigned int*)&XTs[p*136 + s] = (unsigned int)f2bf(x0) | ((unsigned int)f2bf(x1) << 16);
  }
  {
    size_t hb = (((size_t)(b*NH + h))*NCH + c)*4096;
    #pragma unroll
    for (int i = 0; i < 16; i++) {
      int idx = i*256 + tid;
      Hs[(idx >> 6)*72 + (idx & 63)] = f2bf(HIN_[hb + idx]);
    }
  }
  __syncthreads();

  const int wv = tid >> 6, lane = tid & 63, l15 = lane & 15, l4 = lane >> 4;
  const int tb = wv * 32;

  f32x4 g[2][8] = {};
  f32x4 yacc[2][4] = {};
  #pragma unroll
  for (int ks = 0; ks < 2; ks++) {
    int kof = ks*32 + l4*8;
    s16x8 a0 = *(const s16x8*)&Cs[(size_t)(tb      + l15)*72 + kof];
    s16x8 a1 = *(const s16x8*)&Cs[(size_t)(tb + 16 + l15)*72 + kof];
    #pragma unroll
    for (int ni = 0; ni < 8; ni++) {
      if (ni <= 2*wv + 1) {
        s16x8 bfr = *(const s16x8*)&Bs[(size_t)(ni*16 + l15)*72 + kof];
        if (ni <= 2*wv) MFMA(g[0][ni], a0, bfr);
        MFMA(g[1][ni], a1, bfr);
      }
    }
    #pragma unroll
    for (int ni2 = 0; ni2 < 4; ni2++) {
      s16x8 hf = *(const s16x8*)&Hs[(size_t)(ni2*16 + l15)*72 + kof];
      MFMA(yacc[0][ni2], a0, hf);
      MFMA(yacc[1][ni2], a1, hf);
    }
  }
  __syncthreads();

  #pragma unroll
  for (int mi = 0; mi < 2; mi++) {
    #pragma unroll
    for (int ni = 0; ni < 8; ni++) {
      FENCE4(g[mi][ni]);
      int t0 = tb + mi*16 + l4*4;
      int s  = ni*16 + l15;
      float ds = dt_sh[s], cs = cum_sh[s];
      #pragma unroll
      for (int r = 0; r < 4; r++) {
        int tt = t0 + r;
        float val = (s <= tt) ? g[mi][ni][r] * __expf(cum_sh[tt] - cs) * ds : 0.f;
        Ms[(size_t)tt*136 + s] = f2bf(val);
      }
    }
  }

  float er[2][4];
  #pragma unroll
  for (int mi = 0; mi < 2; mi++)
    #pragma unroll
    for (int r = 0; r < 4; r++)
      er[mi][r] = __expf(cum_sh[tb + mi*16 + l4*4 + r]);
  #pragma unroll
  for (int mi = 0; mi < 2; mi++)
    #pragma unroll
    for (int ni2 = 0; ni2 < 4; ni2++) {
      FENCE4(yacc[mi][ni2]);
      #pragma unroll
      for (int r = 0; r < 4; r++) yacc[mi][ni2][r] *= er[mi][r];
      FENCE4(yacc[mi][ni2]);
    }

  #pragma unroll
  for (int ks = 0; ks < 4; ks++) {
    int kof = ks*32 + l4*8;
    s16x8 a0 = *(const s16x8*)&Ms[(size_t)(tb      + l15)*136 + kof];
    s16x8 a1 = *(const s16x8*)&Ms[(size_t)(tb + 16 + l15)*136 + kof];
    #pragma unroll
    for (int ni2 = 0; ni2 < 4; ni2++) {
      s16x8 xf = *(const s16x8*)&XTs[(size_t)(ni2*16 + l15)*136 + kof];
      MFMA(yacc[0][ni2], a0, xf);
      MFMA(yacc[1][ni2], a1, xf);
    }
  }
  #pragma unroll
  for (int mi = 0; mi < 2; mi++)
    #pragma unroll
    for (int ni2 = 0; ni2 < 4; ni2++)
      FENCE4(yacc[mi][ni2]);

  float Dv = Dp_[h];
  #pragma unroll
  for (int mi = 0; mi < 2; mi++) {
    #pragma unroll
    for (int ni2 = 0; ni2 < 4; ni2++) {
      #pragma unroll
      for (int r = 0; r < 4; r++) {
        int t = tb + mi*16 + l4*4 + r;
        int pc = ni2*16 + l15;
        float xv = bf2f(XTs[pc*136 + t]);
        float yv = yacc[mi][ni2][r] + Dv * xv;
        size_t row = row0 + t;
        float zv = ZX_[row*DINP + h*64 + pc];
        Y_[row*DINNER + h*64 + pc] = f2bf(yv * (zv / (1.f + expf(-zv))));
      }
    }
  }
}

// ---------- gated RMSNorm, bf16 in-place ----------
__global__ __launch_bounds__(256) void rms_kernel(
    unsigned short* __restrict__ Y, const float* __restrict__ w)
{
  __shared__ float red[8];
  int row = blockIdx.x, tid = threadIdx.x;
  unsigned short* y = Y + (size_t)row * DINNER;
  float v[8]; float sq = 0.f;
  if (tid < 192) {
    s16x8 u = *(const s16x8*)&y[tid*8];
    #pragma unroll
    for (int i = 0; i < 8; i++) { v[i] = bf2f((unsigned short)u[i]); sq += v[i]*v[i]; }
  }
  float ms = blk_sum(sq, red, tid) * (1.f / 1536.f);
  float rs = rsqrtf(ms + 1e-5f);
  if (tid < 192) {
    const float* wp = w + tid*8;
    union { unsigned short us[8]; uint4 q; } o;
    #pragma unroll
    for (int i = 0; i < 8; i++) o.us[i] = f2bf(v[i] * rs * wp[i]);
    *(uint4*)&y[tid*8] = o.q;
  }
}

// ---------- loss ----------
__global__ void zero_kernel(float* __restrict__ a) { a[0] = 0.f; }

__global__ __launch_bounds__(256) void loss_kernel(
    const float* __restrict__ logits, const int* __restrict__ labels,
    float* __restrict__ acc)
{
  __shared__ float red[8];
  int i = blockIdx.x;
  int b = i / (LL - 1), l = i % (LL - 1);
  const float* lr = logits + ((size_t)b * LL + l) * VOC;
  int tid = threadIdx.x;
  float mx = -1e30f;
  for (int j = tid; j < VOC; j += 256) mx = fmaxf(mx, lr[j]);
  mx = blk_max(mx, red, tid);
  float se = 0.f;
  for (int j = tid; j < VOC; j += 256) se += expf(lr[j] - mx);
  se = blk_sum(se, red, tid);
  if (tid == 0) {
    int lab = labels[b * LL + l + 1];
    float lp = lr[lab] - mx - logf(se);
    atomicAdd(acc, -lp);
  }
}

__global__ void fin_kernel(float* __restrict__ out, const float* __restrict__ acc) {
  out[0] = acc[0] * (1.f / 8188.f);
}

// ---------- launch ----------
extern "C" void kernel_launch(void* const* d_in, const int* in_sizes, int n_in,
                              void* d_out, int out_size, void* d_ws, size_t ws_size,
                              hipStream_t stream)
{
  const float* tok  = (const float*)d_in[0];
  const float* pos  = (const float*)d_in[1];
  const float* lnw  = (const float*)d_in[2];
  const float* lnb  = (const float*)d_in[3];
  const float* ipw  = (const float*)d_in[4];
  const float* cw   = (const float*)d_in[5];
  const float* cb   = (const float*)d_in[6];
  const float* dtb  = (const float*)d_in[7];
  const float* alog = (const float*)d_in[8];
  const float* dpar = (const float*)d_in[9];
  const float* nw   = (const float*)d_in[10];
  const float* opw  = (const float*)d_in[11];
  const float* nfw  = (const float*)d_in[12];
  const float* nfb  = (const float*)d_in[13];
  const float* hw   = (const float*)d_in[14];
  const int*   ids  = (const int*)d_in[15];
  const int*   labs = (const int*)d_in[16];
  float* out = (float*)d_out;

  char* ws = (char*)d_ws;
  float*          X    = (float*)(ws);                   // 8192x768 f32
  float*          XN   = (float*)(ws + 25165824ull);     // 8192x768 f32 (HC alias after dt)
  float*          ZX   = (float*)(ws + 50331648ull);     // 8192x3224 f32
  float*          XC   = (float*)(ws + 155975680ull);    // 8192x1664 f32
  float*          DTv  = (float*)(ws + 210501632ull);    // 8192x24
  float*          LDAv = (float*)(ws + 211288064ull);    // 8192x24
  unsigned short* Ybf  = (unsigned short*)(ws + 212074496ull); // 8192x1536 bf16
  unsigned short* XNb  = (unsigned short*)(ws + 237240320ull); // 8192x768 bf16
  unsigned short* IPWb = (unsigned short*)(ws + 249823232ull); // 3224x768 bf16 (per-layer)
  unsigned short* OPWb = (unsigned short*)(ws + 254775296ull); // 768x1536 bf16 (per-layer)
  unsigned short* HWb  = (unsigned short*)(ws + 257134592ull); // 2048x768 bf16
  float*          ACC  = (float*)(ws + 260280320ull);
  float*          HC   = XN;
  float*          HIN  = out + 1 + 8388608;               // in dead logits region

  embed_kernel<<<ROWS*DIMM/256, 256, 0, stream>>>(tok, pos, ids, X);
  cvt_kernel<<<(VOC*DIMM/8 + 255)/256, 256, 0, stream>>>(hw, HWb, VOC*DIMM/8);

  for (int l = 0; l < NLAYER; l++) {
    cvt_kernel<<<(DINP*DIMM/8 + 255)/256, 256, 0, stream>>>(
        ipw + (size_t)l*DINP*DIMM, IPWb, DINP*DIMM/8);
    cvt_kernel<<<(DIMM*DINNER/8 + 255)/256, 256, 0, stream>>>(
        opw + (size_t)l*DIMM*DINNER, OPWb, DIMM*DINNER/8);

    ln_kernel<<<ROWS, 256, 0, stream>>>(X, lnw + l*DIMM, lnb + l*DIMM, XN, XNb);

    dim3 g1(64, 26);
    gemm_kernel<0><<<g1, 256, 0, stream>>>(XNb, IPWb, ZX, DINP, DIMM, DIMM, DIMM, DINP);

    conv_kernel<<<ROWS*CONVD/256, 256, 0, stream>>>(ZX, cw + l*CONVD*4, cb + l*CONVD, XC);

    dt_kernel<<<ROWS, 256, 0, stream>>>(XN, ipw + (size_t)l*DINP*DIMM,
                                        dtb + l*NH, alog + l*NH, DTv, LDAv);

    dim3 gs(NB*NCH, NH);
    chunkstate_kernel<<<gs, 256, 0, stream>>>(XC, DTv, LDAv, HC);
    scan2_kernel<<<NB*NH, 256, 0, stream>>>(HC, HIN, LDAv);
    ydec_kernel<<<gs, 256, 0, stream>>>(XC, ZX, DTv, LDAv, HIN, dpar + l*NH, Ybf);

    rms_kernel<<<ROWS, 256, 0, stream>>>(Ybf, nw + l*DINNER);

    dim3 g2(64, 6);
    gemm_kernel<1><<<g2, 256, 0, stream>>>(Ybf, OPWb, X, DIMM, DINNER, DINNER, DINNER, DIMM);
  }

  ln_kernel<<<ROWS, 256, 0, stream>>>(X, nfw, nfb, XN, XNb);
  dim3 g3(64, 16);
  gemm_kernel<0><<<g3, 256, 0, stream>>>(XNb, HWb, out + 1, VOC, DIMM, DIMM, DIMM, VOC);

  zero_kernel<<<1, 1, 0, stream>>>(ACC);
  loss_kernel<<<NB*(LL-1), 256, 0, stream>>>(out + 1, labs, ACC);
  fin_kernel<<<1, 1, 0, stream>>>(out, ACC);
}

// Round 5
// 3105.466 us; speedup vs baseline: 9.0006x; 1.4687x over previous
//
#include <hip/hip_runtime.h>
#include <hip/hip_bf16.h>
#include <stdint.h>

#define DIMM   768
#define NLAYER 12
#define DST    64
#define DINNER 1536
#define NH     24
#define CONVD  1664
#define DINP   3224
#define NB     4
#define LL     2048
#define ROWS   (NB*LL)      // 8192
#define VOC    2048
#define Q      128          // SSD chunk length
#define NCH    (LL/Q)       // 16

typedef float f32x4 __attribute__((ext_vector_type(4)));
typedef short s16x8 __attribute__((ext_vector_type(8)));

#define MFMA(acc, a, b) asm volatile("v_mfma_f32_16x16x32_bf16 %0, %1, %2, %0" : "+v"(acc) : "v"(a), "v"(b))
#define FENCE4(v) asm volatile("s_nop 7" : "+v"(v))
#define GLL16(g, l) __builtin_amdgcn_global_load_lds( \
    (const __attribute__((address_space(1))) uint32_t*)(g), \
    (__attribute__((address_space(3))) uint32_t*)(l), 16, 0, 0)

// ---------- helpers ----------
__device__ __forceinline__ unsigned short f2bf(float f) {
  unsigned int u = __float_as_uint(f);
  u = (u + 0x7fffu + ((u >> 16) & 1u)) >> 16;   // RNE
  return (unsigned short)u;
}
__device__ __forceinline__ float bf2f(unsigned short u) {
  return __uint_as_float(((unsigned int)u) << 16);
}
__device__ __forceinline__ float softplus_f(float v) {
  return (v > 20.f) ? v : log1pf(__expf(v));
}

__device__ __forceinline__ uint4 pack8(float4 a, float4 b) {
  union { unsigned short us[8]; uint4 q; } pk;
  pk.us[0] = f2bf(a.x); pk.us[1] = f2bf(a.y); pk.us[2] = f2bf(a.z); pk.us[3] = f2bf(a.w);
  pk.us[4] = f2bf(b.x); pk.us[5] = f2bf(b.y); pk.us[6] = f2bf(b.z); pk.us[7] = f2bf(b.w);
  return pk.q;
}

__device__ __forceinline__ float blk_sum(float v, float* red, int tid) {
  #pragma unroll
  for (int o = 32; o > 0; o >>= 1) v += __shfl_down(v, o, 64);
  __syncthreads();
  if ((tid & 63) == 0) red[tid >> 6] = v;
  __syncthreads();
  return red[0] + red[1] + red[2] + red[3];
}

__device__ __forceinline__ float blk_max(float v, float* red, int tid) {
  #pragma unroll
  for (int o = 32; o > 0; o >>= 1) v = fmaxf(v, __shfl_down(v, o, 64));
  __syncthreads();
  if ((tid & 63) == 0) red[tid >> 6] = v;
  __syncthreads();
  return fmaxf(fmaxf(red[0], red[1]), fmaxf(red[2], red[3]));
}

// ---------- weight cvt: head weight (plain) ----------
__global__ __launch_bounds__(256) void cvt_kernel(
    const float* __restrict__ s, unsigned short* __restrict__ d, int n8)
{
  int i = blockIdx.x * 256 + threadIdx.x;
  if (i < n8) {
    float4 a = ((const float4*)s)[i*2];
    float4 b = ((const float4*)s)[i*2 + 1];
    ((uint4*)d)[i] = pack8(a, b);
  }
}

// ---------- per-layer cvt: in_proj + out_proj*norm_w in one launch ----------
__global__ __launch_bounds__(256) void cvtlayer_kernel(
    const float* __restrict__ ip, const float* __restrict__ op,
    const float* __restrict__ nw, unsigned short* __restrict__ ipb,
    unsigned short* __restrict__ opb)
{
  const int ipn8 = DINP*DIMM/8;
  const int opn8 = DIMM*DINNER/8;
  int i = blockIdx.x * 256 + threadIdx.x;
  if (i < ipn8) {
    float4 a = ((const float4*)ip)[i*2];
    float4 b = ((const float4*)ip)[i*2 + 1];
    ((uint4*)ipb)[i] = pack8(a, b);
  } else if (i < ipn8 + opn8) {
    int j = i - ipn8;
    int k = (j*8) % DINNER;
    float4 a = ((const float4*)op)[j*2];
    float4 b = ((const float4*)op)[j*2 + 1];
    float4 na = *(const float4*)(nw + k);
    float4 nb = *(const float4*)(nw + k + 4);
    a.x *= na.x; a.y *= na.y; a.z *= na.z; a.w *= na.w;
    b.x *= nb.x; b.y *= nb.y; b.z *= nb.z; b.w *= nb.w;
    ((uint4*)opb)[j] = pack8(a, b);
  }
}

// ---------- embedding ----------
__global__ __launch_bounds__(256) void embed_kernel(
    const float* __restrict__ tok, const float* __restrict__ pos,
    const int* __restrict__ ids, float* __restrict__ X)
{
  int idx = blockIdx.x * 256 + threadIdx.x;
  int row = idx / DIMM, d = idx % DIMM;
  int l = row & (LL - 1);
  X[idx] = tok[(size_t)ids[row] * DIMM + d] + pos[(size_t)l * DIMM + d];
}

// ---------- layernorm -> bf16 ----------
__global__ __launch_bounds__(256) void ln_kernel(
    const float* __restrict__ X, const float* __restrict__ w,
    const float* __restrict__ b, unsigned short* __restrict__ Ob)
{
  __shared__ float red[8];
  int row = blockIdx.x, tid = threadIdx.x;
  const float* x = X + (size_t)row * DIMM;
  float v0 = x[tid], v1 = x[tid + 256], v2 = x[tid + 512];
  float mean = blk_sum(v0 + v1 + v2, red, tid) * (1.f / 768.f);
  float d0 = v0 - mean, d1 = v1 - mean, d2 = v2 - mean;
  float var = blk_sum(d0*d0 + d1*d1 + d2*d2, red, tid) * (1.f / 768.f);
  float rs = rsqrtf(var + 1e-5f);
  unsigned short* ob = Ob + (size_t)row * DIMM;
  ob[tid]       = f2bf(d0 * rs * w[tid]       + b[tid]);
  ob[tid + 256] = f2bf(d1 * rs * w[tid + 256] + b[tid + 256]);
  ob[tid + 512] = f2bf(d2 * rs * w[tid + 512] + b[tid + 512]);
}

// ---------- bf16 MFMA GEMM: OUTM 0: f32 C=; 1: f32 C += RS[m]*acc; 2: bf16 C= ----------
template<int OUTM>
__global__ __launch_bounds__(256) void gemm_kernel(
    const unsigned short* __restrict__ A, const unsigned short* __restrict__ W,
    void* __restrict__ Cp, const float* __restrict__ RS,
    int Nreal, int K, int lda, int ldw, int ldc)
{
  __shared__ unsigned short As[128*32];
  __shared__ unsigned short Bs[128*32];
  const int tid = threadIdx.x;
  const int wave = tid >> 6, lane = tid & 63;
  const int wr = wave >> 1, wc = wave & 1;
  const int l15 = lane & 15, l4 = lane >> 4;
  const int bm = blockIdx.x * 128, bn = blockIdx.y * 128;
  f32x4 acc[4][4] = {};

  const int srow = lane >> 2;
  const int scol = (lane & 3) * 8;
  const unsigned short* aptr[2];
  const unsigned short* wptr[2];
  unsigned short* alds[2];
  unsigned short* blds[2];
  #pragma unroll
  for (int j = 0; j < 2; j++) {
    int row = (wave*2 + j)*16 + srow;
    aptr[j] = A + (size_t)(bm + row) * lda + scol;
    int wrow = bn + row; if (wrow > Nreal - 1) wrow = Nreal - 1;
    wptr[j] = W + (size_t)wrow * ldw + scol;
    alds[j] = &As[(wave*2 + j) * 512];
    blds[j] = &Bs[(wave*2 + j) * 512];
  }

  for (int k0 = 0; k0 < K; k0 += 32) {
    __syncthreads();
    #pragma unroll
    for (int j = 0; j < 2; j++) {
      GLL16(aptr[j], alds[j]);
      GLL16(wptr[j], blds[j]);
      aptr[j] += 32; wptr[j] += 32;
    }
    __syncthreads();
    s16x8 af[4], bfr[4];
    #pragma unroll
    for (int mi = 0; mi < 4; mi++)
      af[mi] = *(const s16x8*)&As[(wr*64 + mi*16 + l15)*32 + l4*8];
    #pragma unroll
    for (int ni = 0; ni < 4; ni++)
      bfr[ni] = *(const s16x8*)&Bs[(wc*64 + ni*16 + l15)*32 + l4*8];
    #pragma unroll
    for (int mi = 0; mi < 4; mi++)
      #pragma unroll
      for (int ni = 0; ni < 4; ni++)
        MFMA(acc[mi][ni], af[mi], bfr[ni]);
  }
  #pragma unroll
  for (int mi = 0; mi < 4; mi++)
    #pragma unroll
    for (int ni = 0; ni < 4; ni++)
      FENCE4(acc[mi][ni]);
  const int row0 = bm + wr*64 + l4*4;
  const int colb = bn + wc*64 + l15;
  #pragma unroll
  for (int mi = 0; mi < 4; mi++) {
    #pragma unroll
    for (int ni = 0; ni < 4; ni++) {
      int col = colb + ni*16;
      if (col < Nreal) {
        #pragma unroll
        for (int r = 0; r < 4; r++) {
          int rowm = row0 + mi*16 + r;
          size_t idx = (size_t)rowm * ldc + col;
          if (OUTM == 0)      ((float*)Cp)[idx] = acc[mi][ni][r];
          else if (OUTM == 1) ((float*)Cp)[idx] += RS[rowm] * acc[mi][ni][r];
          else                ((unsigned short*)Cp)[idx] = f2bf(acc[mi][ni][r]);
        }
      }
    }
  }
}

// ---------- causal depthwise conv (taps=4) + bias + silu, bf16 io ----------
__global__ __launch_bounds__(256) void conv_kernel(
    const unsigned short* __restrict__ ZX, const float* __restrict__ cw,
    const float* __restrict__ cb, unsigned short* __restrict__ XC)
{
  int idx = blockIdx.x * 256 + threadIdx.x;   // < 8192*208 exactly
  int c8 = idx % 208, row = idx / 208;
  int c = c8 * 8;
  int l = row & (LL - 1);
  const unsigned short* z = ZX + (size_t)row * DINP + DINNER + c;
  s16x8 x0 = *(const s16x8*)z;
  s16x8 x1 = {}, x2 = {}, x3 = {};
  bool h1 = l >= 1, h2 = l >= 2, h3 = l >= 3;
  if (h1) x1 = *(const s16x8*)(z - DINP);
  if (h2) x2 = *(const s16x8*)(z - 2*DINP);
  if (h3) x3 = *(const s16x8*)(z - 3*DINP);
  union { unsigned short us[8]; uint4 q; } o;
  #pragma unroll
  for (int j = 0; j < 8; j++) {
    float4 w = ((const float4*)cw)[c + j];
    float a = cb[c + j] + bf2f((unsigned short)x0[j]) * w.w;
    if (h1) a += bf2f((unsigned short)x1[j]) * w.z;
    if (h2) a += bf2f((unsigned short)x2[j]) * w.y;
    if (h3) a += bf2f((unsigned short)x3[j]) * w.x;
    o.us[j] = f2bf(a / (1.f + __expf(-a)));
  }
  *(uint4*)(XC + (size_t)row * CONVD + c) = o.q;
}

// ---------- S1: per-chunk state ----------
__global__ __launch_bounds__(256) void chunkstate_kernel(
    const unsigned short* __restrict__ XC_, const unsigned short* __restrict__ ZX_,
    const float* __restrict__ dtbp, const float* __restrict__ alogp,
    float* __restrict__ HC_)
{
  __shared__ unsigned short XT[64*136];
  __shared__ unsigned short BT[64*136];
  __shared__ float cum_sh[Q], wgt_sh[Q];
  __shared__ float carry;
  const int tid = threadIdx.x;
  const int b = blockIdx.x >> 4, c = blockIdx.x & 15, h = blockIdx.y;
  const size_t row0 = (size_t)b*LL + c*Q;

  const float dtbv = dtbp[h];
  const float nA = -__expf(alogp[h]);
  float v = 0.f, dtv = 0.f;
  if (tid < Q) {
    float vraw = bf2f(ZX_[(row0 + tid)*DINP + 3200 + h]) + dtbv;
    dtv = softplus_f(vraw);
    v = dtv * nA;
    #pragma unroll
    for (int off = 1; off < 64; off <<= 1) {
      float u = __shfl_up(v, off, 64);
      if ((tid & 63) >= off) v += u;
    }
  }
  if (tid == 63) carry = v;
  __syncthreads();
  if (tid >= 64 && tid < Q) v += carry;
  if (tid < Q) cum_sh[tid] = v;
  __syncthreads();
  if (tid < Q) wgt_sh[tid] = __expf(cum_sh[Q-1] - v) * dtv;
  __syncthreads();

  const int p  = tid & 63;
  const int s0 = (tid >> 6) * 2;
  const unsigned short* xb = XC_ + row0 * CONVD;
  #pragma unroll
  for (int i = 0; i < 16; i++) {
    int s = s0 + i*8;
    float x0 = bf2f(xb[(size_t)s*CONVD     + h*64 + p]) * wgt_sh[s];
    float x1 = bf2f(xb[(size_t)(s+1)*CONVD + h*64 + p]) * wgt_sh[s+1];
    *(unsigned int*)&XT[p*136 + s] = (unsigned int)f2bf(x0) | ((unsigned int)f2bf(x1) << 16);
    unsigned int bb = (unsigned int)xb[(size_t)s*CONVD + DINNER + p]
                    | ((unsigned int)xb[(size_t)(s+1)*CONVD + DINNER + p] << 16);
    *(unsigned int*)&BT[p*136 + s] = bb;
  }
  __syncthreads();

  const int wave = tid >> 6, lane = tid & 63, l15 = lane & 15, l4 = lane >> 4;
  const int wr = wave >> 1, wc = wave & 1;
  f32x4 acc[2][2] = {};
  #pragma unroll
  for (int ks = 0; ks < 4; ks++) {
    int kof = ks*32 + l4*8;
    s16x8 a0 = *(const s16x8*)&XT[(wr*32      + l15)*136 + kof];
    s16x8 a1 = *(const s16x8*)&XT[(wr*32 + 16 + l15)*136 + kof];
    s16x8 b0 = *(const s16x8*)&BT[(wc*32      + l15)*136 + kof];
    s16x8 b1 = *(const s16x8*)&BT[(wc*32 + 16 + l15)*136 + kof];
    MFMA(acc[0][0], a0, b0); MFMA(acc[0][1], a0, b1);
    MFMA(acc[1][0], a1, b0); MFMA(acc[1][1], a1, b1);
  }
  #pragma unroll
  for (int mi = 0; mi < 2; mi++)
    #pragma unroll
    for (int ni = 0; ni < 2; ni++)
      FENCE4(acc[mi][ni]);
  size_t base = (((size_t)(b*NH + h))*NCH + c)*4096;
  #pragma unroll
  for (int mi = 0; mi < 2; mi++)
    #pragma unroll
    for (int ni = 0; ni < 2; ni++)
      #pragma unroll
      for (int r = 0; r < 4; r++)
        HC_[base + (size_t)(wr*32 + mi*16 + l4*4 + r)*64 + wc*32 + ni*16 + l15] = acc[mi][ni][r];
}

// ---------- S2: inter-chunk recurrence, grid (96,4) ----------
__global__ __launch_bounds__(256) void scan2_kernel(
    const float* __restrict__ HC_, float* __restrict__ HIN_,
    const unsigned short* __restrict__ ZX_, const float* __restrict__ dtbp,
    const float* __restrict__ alogp)
{
  __shared__ float dec[NCH];
  int bh = blockIdx.x, b = bh / NH, h = bh % NH;
  int q = blockIdx.y;
  int t = threadIdx.x;
  const float dtbv = dtbp[h];
  const float nA = -__expf(alogp[h]);
  float part = 0.f;
  #pragma unroll
  for (int i = 0; i < 8; i++) {
    float vraw = bf2f(ZX_[((size_t)b*LL + t*8 + i)*DINP + 3200 + h]) + dtbv;
    part += softplus_f(vraw) * nA;
  }
  #pragma unroll
  for (int off = 1; off < 16; off <<= 1) part += __shfl_xor(part, off, 16);
  if ((t & 15) == 0) dec[t >> 4] = __expf(part);
  __syncthreads();
  float st[4] = {0.f, 0.f, 0.f, 0.f};
  for (int c = 0; c < NCH; c++) {
    float d = dec[c];
    size_t base = ((size_t)bh*NCH + c)*4096 + q*1024;
    #pragma unroll
    for (int i = 0; i < 4; i++) {
      int idx = i*256 + t;
      HIN_[base + idx] = st[i];
      st[i] = st[i]*d + HC_[base + idx];
    }
  }
}

// ---------- S3: Y = (M@X)+exp(cum)*(C@Hin^T)+D*x, gated; bf16 out ----------
__global__ __launch_bounds__(256) void ydec_kernel(
    const unsigned short* __restrict__ XC_, const unsigned short* __restrict__ ZX_,
    const float* __restrict__ dtbp, const float* __restrict__ alogp,
    const float* __restrict__ HIN_, const float* __restrict__ Dp_,
    unsigned short* __restrict__ Y_)
{
  __shared__ unsigned short POOL[128*72*2];
  __shared__ unsigned short Hs[64*72];
  __shared__ unsigned short XTs[64*136];
  __shared__ float cum_sh[Q], dt_sh[Q];
  __shared__ float carry;
  unsigned short* Cs = POOL;
  unsigned short* Bs = POOL + 128*72;
  unsigned short* Ms = POOL;

  const int tid = threadIdx.x;
  const int b = blockIdx.x >> 4, c = blockIdx.x & 15, h = blockIdx.y;
  const size_t row0 = (size_t)b*LL + c*Q;

  const float dtbv = dtbp[h];
  const float nA = -__expf(alogp[h]);
  float v = 0.f, dtv = 0.f;
  if (tid < Q) {
    float vraw = bf2f(ZX_[(row0 + tid)*DINP + 3200 + h]) + dtbv;
    dtv = softplus_f(vraw);
    v = dtv * nA;
    #pragma unroll
    for (int off = 1; off < 64; off <<= 1) {
      float u = __shfl_up(v, off, 64);
      if ((tid & 63) >= off) v += u;
    }
  }
  if (tid == 63) carry = v;
  __syncthreads();
  if (tid >= 64 && tid < Q) v += carry;
  if (tid < Q) { cum_sh[tid] = v; dt_sh[tid] = dtv; }

  const int p  = tid & 63;
  const int s0 = (tid >> 6) * 2;
  const unsigned short* xb = XC_ + row0 * CONVD;
  #pragma unroll
  for (int i = 0; i < 16; i++) {
    int s = s0 + i*8;
    Cs[(size_t)s*72 + p]     = xb[(size_t)s*CONVD     + DINNER + DST + p];
    Cs[(size_t)(s+1)*72 + p] = xb[(size_t)(s+1)*CONVD + DINNER + DST + p];
    Bs[(size_t)s*72 + p]     = xb[(size_t)s*CONVD     + DINNER + p];
    Bs[(size_t)(s+1)*72 + p] = xb[(size_t)(s+1)*CONVD + DINNER + p];
    unsigned int xx = (unsigned int)xb[(size_t)s*CONVD + h*64 + p]
                    | ((unsigned int)xb[(size_t)(s+1)*CONVD + h*64 + p] << 16);
    *(unsigned int*)&XTs[p*136 + s] = xx;
  }
  {
    size_t hb = (((size_t)(b*NH + h))*NCH + c)*4096;
    #pragma unroll
    for (int i = 0; i < 16; i++) {
      int idx = i*256 + tid;
      Hs[(idx >> 6)*72 + (idx & 63)] = f2bf(HIN_[hb + idx]);
    }
  }
  __syncthreads();

  const int wv = tid >> 6, lane = tid & 63, l15 = lane & 15, l4 = lane >> 4;
  const int tb = wv * 32;

  f32x4 g[2][8] = {};
  f32x4 yacc[2][4] = {};
  #pragma unroll
  for (int ks = 0; ks < 2; ks++) {
    int kof = ks*32 + l4*8;
    s16x8 a0 = *(const s16x8*)&Cs[(size_t)(tb      + l15)*72 + kof];
    s16x8 a1 = *(const s16x8*)&Cs[(size_t)(tb + 16 + l15)*72 + kof];
    #pragma unroll
    for (int ni = 0; ni < 8; ni++) {
      if (ni <= 2*wv + 1) {
        s16x8 bfr = *(const s16x8*)&Bs[(size_t)(ni*16 + l15)*72 + kof];
        if (ni <= 2*wv) MFMA(g[0][ni], a0, bfr);
        MFMA(g[1][ni], a1, bfr);
      }
    }
    #pragma unroll
    for (int ni2 = 0; ni2 < 4; ni2++) {
      s16x8 hf = *(const s16x8*)&Hs[(size_t)(ni2*16 + l15)*72 + kof];
      MFMA(yacc[0][ni2], a0, hf);
      MFMA(yacc[1][ni2], a1, hf);
    }
  }
  __syncthreads();

  #pragma unroll
  for (int mi = 0; mi < 2; mi++) {
    #pragma unroll
    for (int ni = 0; ni < 8; ni++) {
      FENCE4(g[mi][ni]);
      int t0 = tb + mi*16 + l4*4;
      int s  = ni*16 + l15;
      float ds = dt_sh[s], cs = cum_sh[s];
      #pragma unroll
      for (int r = 0; r < 4; r++) {
        int tt = t0 + r;
        float val = (s <= tt) ? g[mi][ni][r] * __expf(cum_sh[tt] - cs) * ds : 0.f;
        Ms[(size_t)tt*136 + s] = f2bf(val);
      }
    }
  }

  float er[2][4];
  #pragma unroll
  for (int mi = 0; mi < 2; mi++)
    #pragma unroll
    for (int r = 0; r < 4; r++)
      er[mi][r] = __expf(cum_sh[tb + mi*16 + l4*4 + r]);
  #pragma unroll
  for (int mi = 0; mi < 2; mi++)
    #pragma unroll
    for (int ni2 = 0; ni2 < 4; ni2++) {
      FENCE4(yacc[mi][ni2]);
      #pragma unroll
      for (int r = 0; r < 4; r++) yacc[mi][ni2][r] *= er[mi][r];
      FENCE4(yacc[mi][ni2]);
    }

  #pragma unroll
  for (int ks = 0; ks < 4; ks++) {
    int kof = ks*32 + l4*8;
    s16x8 a0 = *(const s16x8*)&Ms[(size_t)(tb      + l15)*136 + kof];
    s16x8 a1 = *(const s16x8*)&Ms[(size_t)(tb + 16 + l15)*136 + kof];
    #pragma unroll
    for (int ni2 = 0; ni2 < 4; ni2++) {
      s16x8 xf = *(const s16x8*)&XTs[(size_t)(ni2*16 + l15)*136 + kof];
      MFMA(yacc[0][ni2], a0, xf);
      MFMA(yacc[1][ni2], a1, xf);
    }
  }
  #pragma unroll
  for (int mi = 0; mi < 2; mi++)
    #pragma unroll
    for (int ni2 = 0; ni2 < 4; ni2++)
      FENCE4(yacc[mi][ni2]);

  float Dv = Dp_[h];
  #pragma unroll
  for (int mi = 0; mi < 2; mi++) {
    #pragma unroll
    for (int ni2 = 0; ni2 < 4; ni2++) {
      #pragma unroll
      for (int r = 0; r < 4; r++) {
        int t = tb + mi*16 + l4*4 + r;
        int pc = ni2*16 + l15;
        float xv = bf2f(XTs[pc*136 + t]);
        float yv = yacc[mi][ni2][r] + Dv * xv;
        size_t row = row0 + t;
        float zv = bf2f(ZX_[row*DINP + h*64 + pc]);
        Y_[row*DINNER + h*64 + pc] = f2bf(yv * (zv / (1.f + __expf(-zv))));
      }
    }
  }
}

// ---------- per-row RMS scale (norm applied in gemm2 epilogue) ----------
__global__ __launch_bounds__(256) void rs_kernel(
    const unsigned short* __restrict__ Y, float* __restrict__ RS)
{
  __shared__ float red[8];
  int row = blockIdx.x, tid = threadIdx.x;
  const unsigned short* y = Y + (size_t)row * DINNER;
  float sq = 0.f;
  if (tid < 192) {
    s16x8 u = *(const s16x8*)&y[tid*8];
    #pragma unroll
    for (int i = 0; i < 8; i++) { float f = bf2f((unsigned short)u[i]); sq += f*f; }
  }
  float ms = blk_sum(sq, red, tid) * (1.f / 1536.f);
  if (tid == 0) RS[row] = rsqrtf(ms + 1e-5f);
}

// ---------- loss (one-pass online logsumexp) ----------
__global__ void zero_kernel(float* __restrict__ a) { a[0] = 0.f; }

__global__ __launch_bounds__(256) void loss_kernel(
    const float* __restrict__ logits, const int* __restrict__ labels,
    float* __restrict__ acc)
{
  __shared__ float red[8];
  int i = blockIdx.x;
  int b = i / (LL - 1), l = i % (LL - 1);
  const float* lr = logits + ((size_t)b * LL + l) * VOC;
  int tid = threadIdx.x;
  float4 v0 = ((const float4*)lr)[tid*2];
  float4 v1 = ((const float4*)lr)[tid*2 + 1];
  float mx = fmaxf(fmaxf(fmaxf(v0.x, v0.y), fmaxf(v0.z, v0.w)),
                   fmaxf(fmaxf(v1.x, v1.y), fmaxf(v1.z, v1.w)));
  mx = blk_max(mx, red, tid);
  float se = __expf(v0.x - mx) + __expf(v0.y - mx) + __expf(v0.z - mx) + __expf(v0.w - mx)
           + __expf(v1.x - mx) + __expf(v1.y - mx) + __expf(v1.z - mx) + __expf(v1.w - mx);
  se = blk_sum(se, red, tid);
  if (tid == 0) {
    int lab = labels[b * LL + l + 1];
    float lp = lr[lab] - mx - __logf(se);
    atomicAdd(acc, -lp);
  }
}

__global__ void fin_kernel(float* __restrict__ out, const float* __restrict__ acc) {
  out[0] = acc[0] * (1.f / 8188.f);
}

// ---------- launch ----------
extern "C" void kernel_launch(void* const* d_in, const int* in_sizes, int n_in,
                              void* d_out, int out_size, void* d_ws, size_t ws_size,
                              hipStream_t stream)
{
  const float* tok  = (const float*)d_in[0];
  const float* pos  = (const float*)d_in[1];
  const float* lnw  = (const float*)d_in[2];
  const float* lnb  = (const float*)d_in[3];
  const float* ipw  = (const float*)d_in[4];
  const float* cw   = (const float*)d_in[5];
  const float* cb   = (const float*)d_in[6];
  const float* dtb  = (const float*)d_in[7];
  const float* alog = (const float*)d_in[8];
  const float* dpar = (const float*)d_in[9];
  const float* nw   = (const float*)d_in[10];
  const float* opw  = (const float*)d_in[11];
  const float* nfw  = (const float*)d_in[12];
  const float* nfb  = (const float*)d_in[13];
  const float* hw   = (const float*)d_in[14];
  const int*   ids  = (const int*)d_in[15];
  const int*   labs = (const int*)d_in[16];
  float* out = (float*)d_out;

  char* ws = (char*)d_ws;
  float*          X    = (float*)(ws);                          // 8192x768 f32
  unsigned short* ZX   = (unsigned short*)(ws +  25165824ull);  // 8192x3224 bf16
  unsigned short* XC   = (unsigned short*)(ws +  77987840ull);  // 8192x1664 bf16
  unsigned short* Ybf  = (unsigned short*)(ws + 105250816ull);  // 8192x1536 bf16
  unsigned short* XNb  = (unsigned short*)(ws + 130416640ull);  // 8192x768 bf16
  unsigned short* IPWb = (unsigned short*)(ws + 142999552ull);  // 3224x768 bf16
  unsigned short* OPWb = (unsigned short*)(ws + 147951616ull);  // 768x1536 bf16 (x norm_w)
  unsigned short* HWb  = (unsigned short*)(ws + 150310912ull);  // 2048x768 bf16
  float*          HC   = (float*)(ws + 153456640ull);           // 96*16*4096 f32
  float*          RS   = (float*)(ws + 178622464ull);           // 8192 f32
  float*          ACC  = (float*)(ws + 178655232ull);           // 1
  float*          HIN  = out + 1 + 8388608;                     // 6.29M f32 in dead logits region

  embed_kernel<<<ROWS*DIMM/256, 256, 0, stream>>>(tok, pos, ids, X);
  cvt_kernel<<<(VOC*DIMM/8 + 255)/256, 256, 0, stream>>>(hw, HWb, VOC*DIMM/8);

  const int cvtg = (DINP*DIMM/8 + DIMM*DINNER/8 + 255)/256;
  for (int l = 0; l < NLAYER; l++) {
    cvtlayer_kernel<<<cvtg, 256, 0, stream>>>(
        ipw + (size_t)l*DINP*DIMM, opw + (size_t)l*DIMM*DINNER,
        nw + (size_t)l*DINNER, IPWb, OPWb);

    ln_kernel<<<ROWS, 256, 0, stream>>>(X, lnw + l*DIMM, lnb + l*DIMM, XNb);

    dim3 g1(64, 26);
    gemm_kernel<2><<<g1, 256, 0, stream>>>(XNb, IPWb, ZX, nullptr,
                                           DINP, DIMM, DIMM, DIMM, DINP);

    conv_kernel<<<ROWS*208/256, 256, 0, stream>>>(ZX, cw + l*CONVD*4, cb + l*CONVD, XC);

    dim3 gs(NB*NCH, NH);
    chunkstate_kernel<<<gs, 256, 0, stream>>>(XC, ZX, dtb + l*NH, alog + l*NH, HC);
    dim3 g2s(NB*NH, 4);
    scan2_kernel<<<g2s, 256, 0, stream>>>(HC, HIN, ZX, dtb + l*NH, alog + l*NH);
    ydec_kernel<<<gs, 256, 0, stream>>>(XC, ZX, dtb + l*NH, alog + l*NH, HIN,
                                        dpar + l*NH, Ybf);

    rs_kernel<<<ROWS, 256, 0, stream>>>(Ybf, RS);

    dim3 g2(64, 6);
    gemm_kernel<1><<<g2, 256, 0, stream>>>(Ybf, OPWb, X, RS,
                                           DIMM, DINNER, DINNER, DINNER, DIMM);
  }

  ln_kernel<<<ROWS, 256, 0, stream>>>(X, nfw, nfb, XNb);
  dim3 g3(64, 16);
  gemm_kernel<0><<<g3, 256, 0, stream>>>(XNb, HWb, out + 1, nullptr,
                                         VOC, DIMM, DIMM, DIMM, VOC);

  zero_kernel<<<1, 1, 0, stream>>>(ACC);
  loss_kernel<<<NB*(LL-1), 256, 0, stream>>>(out + 1, labs, ACC);
  fin_kernel<<<1, 1, 0, stream>>>(out, ACC);
}

// Round 6
// 3081.652 us; speedup vs baseline: 9.0702x; 1.0077x over previous
//
#include <hip/hip_runtime.h>
#include <hip/hip_bf16.h>
#include <stdint.h>

#define DIMM   768
#define NLAYER 12
#define DST    64
#define DINNER 1536
#define NH     24
#define CONVD  1664
#define DINP   3224
#define NB     4
#define LL     2048
#define ROWS   (NB*LL)      // 8192
#define VOC    2048
#define Q      128          // SSD chunk length
#define NCH    (LL/Q)       // 16

typedef float f32x4 __attribute__((ext_vector_type(4)));
typedef short s16x8 __attribute__((ext_vector_type(8)));

#define MFMA(acc, a, b) asm volatile("v_mfma_f32_16x16x32_bf16 %0, %1, %2, %0" : "+v"(acc) : "v"(a), "v"(b))
#define FENCE4(v) asm volatile("s_nop 7" : "+v"(v))
#define GLL16(g, l) __builtin_amdgcn_global_load_lds( \
    (const __attribute__((address_space(1))) uint32_t*)(g), \
    (__attribute__((address_space(3))) uint32_t*)(l), 16, 0, 0)

// ---------- helpers ----------
__device__ __forceinline__ unsigned short f2bf(float f) {
  unsigned int u = __float_as_uint(f);
  u = (u + 0x7fffu + ((u >> 16) & 1u)) >> 16;   // RNE
  return (unsigned short)u;
}
__device__ __forceinline__ float bf2f(unsigned short u) {
  return __uint_as_float(((unsigned int)u) << 16);
}
__device__ __forceinline__ float softplus_f(float v) {
  return (v > 20.f) ? v : log1pf(__expf(v));
}

__device__ __forceinline__ uint4 pack8(float4 a, float4 b) {
  union { unsigned short us[8]; uint4 q; } pk;
  pk.us[0] = f2bf(a.x); pk.us[1] = f2bf(a.y); pk.us[2] = f2bf(a.z); pk.us[3] = f2bf(a.w);
  pk.us[4] = f2bf(b.x); pk.us[5] = f2bf(b.y); pk.us[6] = f2bf(b.z); pk.us[7] = f2bf(b.w);
  return pk.q;
}

__device__ __forceinline__ float blk_sum(float v, float* red, int tid) {
  #pragma unroll
  for (int o = 32; o > 0; o >>= 1) v += __shfl_down(v, o, 64);
  __syncthreads();
  if ((tid & 63) == 0) red[tid >> 6] = v;
  __syncthreads();
  return red[0] + red[1] + red[2] + red[3];
}

// ---------- ALL weight cvts in one launch ----------
__global__ __launch_bounds__(256) void cvtall_kernel(
    const float* __restrict__ ipw, const float* __restrict__ opw,
    const float* __restrict__ nw, const float* __restrict__ hw,
    unsigned short* __restrict__ ipb, unsigned short* __restrict__ opb,
    unsigned short* __restrict__ hwb)
{
  const int IPN8 = NLAYER*DINP*DIMM/8;     // 3,714,048
  const int OPN8 = NLAYER*DIMM*DINNER/8;   // 1,769,472
  const int HWN8 = VOC*DIMM/8;             //   196,608
  int i = blockIdx.x * 256 + threadIdx.x;
  if (i < IPN8) {
    float4 a = ((const float4*)ipw)[i*2];
    float4 b = ((const float4*)ipw)[i*2 + 1];
    ((uint4*)ipb)[i] = pack8(a, b);
  } else if (i < IPN8 + OPN8) {
    int j = i - IPN8;
    int layer = j / (DIMM*DINNER/8);
    int k = (j*8) % DINNER;
    const float* nwl = nw + layer*DINNER;
    float4 a = ((const float4*)opw)[j*2];
    float4 b = ((const float4*)opw)[j*2 + 1];
    float4 na = *(const float4*)(nwl + k);
    float4 nb = *(const float4*)(nwl + k + 4);
    a.x *= na.x; a.y *= na.y; a.z *= na.z; a.w *= na.w;
    b.x *= nb.x; b.y *= nb.y; b.z *= nb.z; b.w *= nb.w;
    ((uint4*)opb)[j] = pack8(a, b);
  } else if (i < IPN8 + OPN8 + HWN8) {
    int j = i - IPN8 - OPN8;
    ((uint4*)hwb)[j] = pack8(((const float4*)hw)[j*2], ((const float4*)hw)[j*2 + 1]);
  }
}

// ---------- embedding ----------
__global__ __launch_bounds__(256) void embed_kernel(
    const float* __restrict__ tok, const float* __restrict__ pos,
    const int* __restrict__ ids, float* __restrict__ X)
{
  int idx = blockIdx.x * 256 + threadIdx.x;
  int row = idx / DIMM, d = idx % DIMM;
  int l = row & (LL - 1);
  X[idx] = tok[(size_t)ids[row] * DIMM + d] + pos[(size_t)l * DIMM + d];
}

// ---------- layernorm -> bf16 ----------
__global__ __launch_bounds__(256) void ln_kernel(
    const float* __restrict__ X, const float* __restrict__ w,
    const float* __restrict__ b, unsigned short* __restrict__ Ob)
{
  __shared__ float red[8];
  int row = blockIdx.x, tid = threadIdx.x;
  const float* x = X + (size_t)row * DIMM;
  float v0 = x[tid], v1 = x[tid + 256], v2 = x[tid + 512];
  float mean = blk_sum(v0 + v1 + v2, red, tid) * (1.f / 768.f);
  float d0 = v0 - mean, d1 = v1 - mean, d2 = v2 - mean;
  float var = blk_sum(d0*d0 + d1*d1 + d2*d2, red, tid) * (1.f / 768.f);
  float rs = rsqrtf(var + 1e-5f);
  unsigned short* ob = Ob + (size_t)row * DIMM;
  ob[tid]       = f2bf(d0 * rs * w[tid]       + b[tid]);
  ob[tid + 256] = f2bf(d1 * rs * w[tid + 256] + b[tid + 256]);
  ob[tid + 512] = f2bf(d2 * rs * w[tid + 512] + b[tid + 512]);
}

// ---------- bf16 MFMA GEMM: OUTM 0: f32 C=; 1: f32 C += rsqrt(RS[m]/1536+eps)*acc; 2: bf16 C= ----------
template<int OUTM>
__global__ __launch_bounds__(256) void gemm_kernel(
    const unsigned short* __restrict__ A, const unsigned short* __restrict__ W,
    void* __restrict__ Cp, const float* __restrict__ RS,
    int Nreal, int K, int lda, int ldw, int ldc)
{
  __shared__ unsigned short As[128*32];
  __shared__ unsigned short Bs[128*32];
  const int tid = threadIdx.x;
  const int wave = tid >> 6, lane = tid & 63;
  const int wr = wave >> 1, wc = wave & 1;
  const int l15 = lane & 15, l4 = lane >> 4;
  const int bm = blockIdx.x * 128, bn = blockIdx.y * 128;
  f32x4 acc[4][4] = {};

  const int srow = lane >> 2;
  const int scol = (lane & 3) * 8;
  const unsigned short* aptr[2];
  const unsigned short* wptr[2];
  unsigned short* alds[2];
  unsigned short* blds[2];
  #pragma unroll
  for (int j = 0; j < 2; j++) {
    int row = (wave*2 + j)*16 + srow;
    aptr[j] = A + (size_t)(bm + row) * lda + scol;
    int wrow = bn + row; if (wrow > Nreal - 1) wrow = Nreal - 1;
    wptr[j] = W + (size_t)wrow * ldw + scol;
    alds[j] = &As[(wave*2 + j) * 512];
    blds[j] = &Bs[(wave*2 + j) * 512];
  }

  for (int k0 = 0; k0 < K; k0 += 32) {
    __syncthreads();
    #pragma unroll
    for (int j = 0; j < 2; j++) {
      GLL16(aptr[j], alds[j]);
      GLL16(wptr[j], blds[j]);
      aptr[j] += 32; wptr[j] += 32;
    }
    __syncthreads();
    s16x8 af[4], bfr[4];
    #pragma unroll
    for (int mi = 0; mi < 4; mi++)
      af[mi] = *(const s16x8*)&As[(wr*64 + mi*16 + l15)*32 + l4*8];
    #pragma unroll
    for (int ni = 0; ni < 4; ni++)
      bfr[ni] = *(const s16x8*)&Bs[(wc*64 + ni*16 + l15)*32 + l4*8];
    #pragma unroll
    for (int mi = 0; mi < 4; mi++)
      #pragma unroll
      for (int ni = 0; ni < 4; ni++)
        MFMA(acc[mi][ni], af[mi], bfr[ni]);
  }
  #pragma unroll
  for (int mi = 0; mi < 4; mi++)
    #pragma unroll
    for (int ni = 0; ni < 4; ni++)
      FENCE4(acc[mi][ni]);
  const int row0 = bm + wr*64 + l4*4;
  const int colb = bn + wc*64 + l15;
  #pragma unroll
  for (int mi = 0; mi < 4; mi++) {
    #pragma unroll
    for (int ni = 0; ni < 4; ni++) {
      int col = colb + ni*16;
      if (col < Nreal) {
        #pragma unroll
        for (int r = 0; r < 4; r++) {
          int rowm = row0 + mi*16 + r;
          size_t idx = (size_t)rowm * ldc + col;
          if (OUTM == 0)      ((float*)Cp)[idx] = acc[mi][ni][r];
          else if (OUTM == 1) {
            float rsv = rsqrtf(RS[rowm] * (1.f/1536.f) + 1e-5f);
            ((float*)Cp)[idx] += rsv * acc[mi][ni][r];
          }
          else                ((unsigned short*)Cp)[idx] = f2bf(acc[mi][ni][r]);
        }
      }
    }
  }
}

// ---------- causal depthwise conv + bias + silu, bf16 io; zeroes RS as side job ----------
__global__ __launch_bounds__(256) void conv_kernel(
    const unsigned short* __restrict__ ZX, const float* __restrict__ cw,
    const float* __restrict__ cb, unsigned short* __restrict__ XC,
    float* __restrict__ RS)
{
  int idx = blockIdx.x * 256 + threadIdx.x;   // < 8192*208 exactly
  if (idx < ROWS) RS[idx] = 0.f;
  int c8 = idx % 208, row = idx / 208;
  int c = c8 * 8;
  int l = row & (LL - 1);
  const unsigned short* z = ZX + (size_t)row * DINP + DINNER + c;
  s16x8 x0 = *(const s16x8*)z;
  s16x8 x1 = {}, x2 = {}, x3 = {};
  bool h1 = l >= 1, h2 = l >= 2, h3 = l >= 3;
  if (h1) x1 = *(const s16x8*)(z - DINP);
  if (h2) x2 = *(const s16x8*)(z - 2*DINP);
  if (h3) x3 = *(const s16x8*)(z - 3*DINP);
  union { unsigned short us[8]; uint4 q; } o;
  #pragma unroll
  for (int j = 0; j < 8; j++) {
    float4 w = ((const float4*)cw)[c + j];
    float a = cb[c + j] + bf2f((unsigned short)x0[j]) * w.w;
    if (h1) a += bf2f((unsigned short)x1[j]) * w.z;
    if (h2) a += bf2f((unsigned short)x2[j]) * w.y;
    if (h3) a += bf2f((unsigned short)x3[j]) * w.x;
    o.us[j] = f2bf(a / (1.f + __expf(-a)));
  }
  *(uint4*)(XC + (size_t)row * CONVD + c) = o.q;
}

// ---------- S1: per-chunk state; also emits (cum,dt) pairs + chunk decay ----------
__global__ __launch_bounds__(256) void chunkstate_kernel(
    const unsigned short* __restrict__ XC_, const unsigned short* __restrict__ ZX_,
    const float* __restrict__ dtbp, const float* __restrict__ alogp,
    float* __restrict__ HC_, float2* __restrict__ DTC_, float* __restrict__ CDEC_)
{
  __shared__ unsigned short XT[64*136];
  __shared__ unsigned short BT[64*136];
  __shared__ float cum_sh[Q], wgt_sh[Q];
  __shared__ float carry;
  const int tid = threadIdx.x;
  const int b = blockIdx.x >> 4, c = blockIdx.x & 15, h = blockIdx.y;
  const size_t row0 = (size_t)b*LL + c*Q;
  const size_t bhc = (size_t)(b*NH + h)*NCH + c;

  const float dtbv = dtbp[h];
  const float nA = -__expf(alogp[h]);
  float v = 0.f, dtv = 0.f;
  if (tid < Q) {
    float vraw = bf2f(ZX_[(row0 + tid)*DINP + 3200 + h]) + dtbv;
    dtv = softplus_f(vraw);
    v = dtv * nA;
    #pragma unroll
    for (int off = 1; off < 64; off <<= 1) {
      float u = __shfl_up(v, off, 64);
      if ((tid & 63) >= off) v += u;
    }
  }
  if (tid == 63) carry = v;
  __syncthreads();
  if (tid >= 64 && tid < Q) v += carry;
  if (tid < Q) cum_sh[tid] = v;
  __syncthreads();
  if (tid < Q) {
    wgt_sh[tid] = __expf(cum_sh[Q-1] - v) * dtv;
    float2 cd; cd.x = v; cd.y = dtv;
    DTC_[bhc*Q + tid] = cd;
  }
  if (tid == Q-1) CDEC_[bhc] = __expf(v);
  __syncthreads();

  const int p  = tid & 63;
  const int s0 = (tid >> 6) * 2;
  const unsigned short* xb = XC_ + row0 * CONVD;
  #pragma unroll
  for (int i = 0; i < 16; i++) {
    int s = s0 + i*8;
    float x0 = bf2f(xb[(size_t)s*CONVD     + h*64 + p]) * wgt_sh[s];
    float x1 = bf2f(xb[(size_t)(s+1)*CONVD + h*64 + p]) * wgt_sh[s+1];
    *(unsigned int*)&XT[p*136 + s] = (unsigned int)f2bf(x0) | ((unsigned int)f2bf(x1) << 16);
    unsigned int bb = (unsigned int)xb[(size_t)s*CONVD + DINNER + p]
                    | ((unsigned int)xb[(size_t)(s+1)*CONVD + DINNER + p] << 16);
    *(unsigned int*)&BT[p*136 + s] = bb;
  }
  __syncthreads();

  const int wave = tid >> 6, lane = tid & 63, l15 = lane & 15, l4 = lane >> 4;
  const int wr = wave >> 1, wc = wave & 1;
  f32x4 acc[2][2] = {};
  #pragma unroll
  for (int ks = 0; ks < 4; ks++) {
    int kof = ks*32 + l4*8;
    s16x8 a0 = *(const s16x8*)&XT[(wr*32      + l15)*136 + kof];
    s16x8 a1 = *(const s16x8*)&XT[(wr*32 + 16 + l15)*136 + kof];
    s16x8 b0 = *(const s16x8*)&BT[(wc*32      + l15)*136 + kof];
    s16x8 b1 = *(const s16x8*)&BT[(wc*32 + 16 + l15)*136 + kof];
    MFMA(acc[0][0], a0, b0); MFMA(acc[0][1], a0, b1);
    MFMA(acc[1][0], a1, b0); MFMA(acc[1][1], a1, b1);
  }
  #pragma unroll
  for (int mi = 0; mi < 2; mi++)
    #pragma unroll
    for (int ni = 0; ni < 2; ni++)
      FENCE4(acc[mi][ni]);
  size_t base = bhc*4096;
  #pragma unroll
  for (int mi = 0; mi < 2; mi++)
    #pragma unroll
    for (int ni = 0; ni < 2; ni++)
      #pragma unroll
      for (int r = 0; r < 4; r++)
        HC_[base + (size_t)(wr*32 + mi*16 + l4*4 + r)*64 + wc*32 + ni*16 + l15] = acc[mi][ni][r];
}

// ---------- S2: inter-chunk recurrence, grid (96,4) ----------
__global__ __launch_bounds__(256) void scan2_kernel(
    const float* __restrict__ HC_, float* __restrict__ HIN_,
    const float* __restrict__ CDEC_)
{
  __shared__ float dec[NCH];
  int bh = blockIdx.x;
  int q = blockIdx.y;
  int t = threadIdx.x;
  if (t < NCH) dec[t] = CDEC_[bh*NCH + t];
  __syncthreads();
  float st[4] = {0.f, 0.f, 0.f, 0.f};
  for (int c = 0; c < NCH; c++) {
    float d = dec[c];
    size_t base = ((size_t)bh*NCH + c)*4096 + q*1024;
    #pragma unroll
    for (int i = 0; i < 4; i++) {
      int idx = i*256 + t;
      HIN_[base + idx] = st[i];
      st[i] = st[i]*d + HC_[base + idx];
    }
  }
}

// ---------- S3: Y = (M@X)+exp(cum)*(C@Hin^T)+D*x, gated; bf16 out + sumsq atomics ----------
__global__ __launch_bounds__(256) void ydec_kernel(
    const unsigned short* __restrict__ XC_, const unsigned short* __restrict__ ZX_,
    const float2* __restrict__ DTC_, const float* __restrict__ HIN_,
    const float* __restrict__ Dp_, unsigned short* __restrict__ Y_,
    float* __restrict__ RS_)
{
  __shared__ unsigned short POOL[128*72*2];
  __shared__ unsigned short Hs[64*72];
  __shared__ unsigned short XTs[64*136];
  __shared__ float cum_sh[Q], dt_sh[Q];
  unsigned short* Cs = POOL;
  unsigned short* Bs = POOL + 128*72;
  unsigned short* Ms = POOL;

  const int tid = threadIdx.x;
  const int b = blockIdx.x >> 4, c = blockIdx.x & 15, h = blockIdx.y;
  const size_t row0 = (size_t)b*LL + c*Q;
  const size_t bhc = (size_t)(b*NH + h)*NCH + c;

  if (tid < Q) {
    float2 cd = DTC_[bhc*Q + tid];
    cum_sh[tid] = cd.x; dt_sh[tid] = cd.y;
  }

  const int p  = tid & 63;
  const int s0 = (tid >> 6) * 2;
  const unsigned short* xb = XC_ + row0 * CONVD;
  #pragma unroll
  for (int i = 0; i < 16; i++) {
    int s = s0 + i*8;
    Cs[(size_t)s*72 + p]     = xb[(size_t)s*CONVD     + DINNER + DST + p];
    Cs[(size_t)(s+1)*72 + p] = xb[(size_t)(s+1)*CONVD + DINNER + DST + p];
    Bs[(size_t)s*72 + p]     = xb[(size_t)s*CONVD     + DINNER + p];
    Bs[(size_t)(s+1)*72 + p] = xb[(size_t)(s+1)*CONVD + DINNER + p];
    unsigned int xx = (unsigned int)xb[(size_t)s*CONVD + h*64 + p]
                    | ((unsigned int)xb[(size_t)(s+1)*CONVD + h*64 + p] << 16);
    *(unsigned int*)&XTs[p*136 + s] = xx;
  }
  {
    size_t hb = bhc*4096;
    #pragma unroll
    for (int i = 0; i < 16; i++) {
      int idx = i*256 + tid;
      Hs[(idx >> 6)*72 + (idx & 63)] = f2bf(HIN_[hb + idx]);
    }
  }
  __syncthreads();

  const int wv = tid >> 6, lane = tid & 63, l15 = lane & 15, l4 = lane >> 4;
  const int tb = wv * 32;

  f32x4 g[2][8] = {};
  f32x4 yacc[2][4] = {};
  #pragma unroll
  for (int ks = 0; ks < 2; ks++) {
    int kof = ks*32 + l4*8;
    s16x8 a0 = *(const s16x8*)&Cs[(size_t)(tb      + l15)*72 + kof];
    s16x8 a1 = *(const s16x8*)&Cs[(size_t)(tb + 16 + l15)*72 + kof];
    #pragma unroll
    for (int ni = 0; ni < 8; ni++) {
      if (ni <= 2*wv + 1) {
        s16x8 bfr = *(const s16x8*)&Bs[(size_t)(ni*16 + l15)*72 + kof];
        if (ni <= 2*wv) MFMA(g[0][ni], a0, bfr);
        MFMA(g[1][ni], a1, bfr);
      }
    }
    #pragma unroll
    for (int ni2 = 0; ni2 < 4; ni2++) {
      s16x8 hf = *(const s16x8*)&Hs[(size_t)(ni2*16 + l15)*72 + kof];
      MFMA(yacc[0][ni2], a0, hf);
      MFMA(yacc[1][ni2], a1, hf);
    }
  }
  __syncthreads();

  #pragma unroll
  for (int mi = 0; mi < 2; mi++) {
    #pragma unroll
    for (int ni = 0; ni < 8; ni++) {
      FENCE4(g[mi][ni]);
      int t0 = tb + mi*16 + l4*4;
      int s  = ni*16 + l15;
      float ds = dt_sh[s], cs = cum_sh[s];
      #pragma unroll
      for (int r = 0; r < 4; r++) {
        int tt = t0 + r;
        float val = (s <= tt) ? g[mi][ni][r] * __expf(cum_sh[tt] - cs) * ds : 0.f;
        Ms[(size_t)tt*136 + s] = f2bf(val);
      }
    }
  }

  float er[2][4];
  #pragma unroll
  for (int mi = 0; mi < 2; mi++)
    #pragma unroll
    for (int r = 0; r < 4; r++)
      er[mi][r] = __expf(cum_sh[tb + mi*16 + l4*4 + r]);
  #pragma unroll
  for (int mi = 0; mi < 2; mi++)
    #pragma unroll
    for (int ni2 = 0; ni2 < 4; ni2++) {
      FENCE4(yacc[mi][ni2]);
      #pragma unroll
      for (int r = 0; r < 4; r++) yacc[mi][ni2][r] *= er[mi][r];
      FENCE4(yacc[mi][ni2]);
    }

  #pragma unroll
  for (int ks = 0; ks < 4; ks++) {
    int kof = ks*32 + l4*8;
    s16x8 a0 = *(const s16x8*)&Ms[(size_t)(tb      + l15)*136 + kof];
    s16x8 a1 = *(const s16x8*)&Ms[(size_t)(tb + 16 + l15)*136 + kof];
    #pragma unroll
    for (int ni2 = 0; ni2 < 4; ni2++) {
      s16x8 xf = *(const s16x8*)&XTs[(size_t)(ni2*16 + l15)*136 + kof];
      MFMA(yacc[0][ni2], a0, xf);
      MFMA(yacc[1][ni2], a1, xf);
    }
  }
  #pragma unroll
  for (int mi = 0; mi < 2; mi++)
    #pragma unroll
    for (int ni2 = 0; ni2 < 4; ni2++)
      FENCE4(yacc[mi][ni2]);

  float Dv = Dp_[h];
  float sq[2][4] = {};
  #pragma unroll
  for (int mi = 0; mi < 2; mi++) {
    #pragma unroll
    for (int ni2 = 0; ni2 < 4; ni2++) {
      #pragma unroll
      for (int r = 0; r < 4; r++) {
        int t = tb + mi*16 + l4*4 + r;
        int pc = ni2*16 + l15;
        float xv = bf2f(XTs[pc*136 + t]);
        float yv = yacc[mi][ni2][r] + Dv * xv;
        size_t row = row0 + t;
        float zv = bf2f(ZX_[row*DINP + h*64 + pc]);
        float yg = yv * (zv / (1.f + __expf(-zv)));
        Y_[row*DINNER + h*64 + pc] = f2bf(yg);
        sq[mi][r] += yg * yg;
      }
    }
  }
  // per-row sumsq: reduce over l15 group (16 lanes share a row), one atomic per group
  #pragma unroll
  for (int mi = 0; mi < 2; mi++) {
    #pragma unroll
    for (int r = 0; r < 4; r++) {
      float vsum = sq[mi][r];
      #pragma unroll
      for (int off = 1; off < 16; off <<= 1) vsum += __shfl_xor(vsum, off, 64);
      if (l15 == 0)
        atomicAdd(&RS_[row0 + tb + mi*16 + l4*4 + r], vsum);
    }
  }
}

// ---------- loss: one wave per row ----------
__global__ void zero_kernel(float* __restrict__ a) { a[0] = 0.f; }

__global__ __launch_bounds__(256) void loss_kernel(
    const float* __restrict__ logits, const int* __restrict__ labels,
    float* __restrict__ acc)
{
  __shared__ float red[4];
  int wv = threadIdx.x >> 6, lane = threadIdx.x & 63;
  int i = blockIdx.x * 4 + wv;          // grid 2047 -> i in [0, 8188)
  int b = i / (LL - 1), l = i % (LL - 1);
  const float* lr = logits + ((size_t)b * LL + l) * VOC;
  const float4* lr4 = (const float4*)lr;
  float4 v[8];
  #pragma unroll
  for (int j = 0; j < 8; j++) v[j] = lr4[j*64 + lane];
  float mx = -1e30f;
  #pragma unroll
  for (int j = 0; j < 8; j++)
    mx = fmaxf(mx, fmaxf(fmaxf(v[j].x, v[j].y), fmaxf(v[j].z, v[j].w)));
  #pragma unroll
  for (int o = 32; o > 0; o >>= 1) mx = fmaxf(mx, __shfl_xor(mx, o, 64));
  float se = 0.f;
  #pragma unroll
  for (int j = 0; j < 8; j++)
    se += __expf(v[j].x - mx) + __expf(v[j].y - mx)
        + __expf(v[j].z - mx) + __expf(v[j].w - mx);
  #pragma unroll
  for (int o = 32; o > 0; o >>= 1) se += __shfl_xor(se, o, 64);
  if (lane == 0) {
    int lab = labels[b * LL + l + 1];
    red[wv] = lr[lab] - mx - __logf(se);
  }
  __syncthreads();
  if (threadIdx.x == 0)
    atomicAdd(acc, -(red[0] + red[1] + red[2] + red[3]));
}

__global__ void fin_kernel(float* __restrict__ out, const float* __restrict__ acc) {
  out[0] = acc[0] * (1.f / 8188.f);
}

// ---------- launch ----------
extern "C" void kernel_launch(void* const* d_in, const int* in_sizes, int n_in,
                              void* d_out, int out_size, void* d_ws, size_t ws_size,
                              hipStream_t stream)
{
  const float* tok  = (const float*)d_in[0];
  const float* pos  = (const float*)d_in[1];
  const float* lnw  = (const float*)d_in[2];
  const float* lnb  = (const float*)d_in[3];
  const float* ipw  = (const float*)d_in[4];
  const float* cw   = (const float*)d_in[5];
  const float* cb   = (const float*)d_in[6];
  const float* dtb  = (const float*)d_in[7];
  const float* alog = (const float*)d_in[8];
  const float* dpar = (const float*)d_in[9];
  const float* nw   = (const float*)d_in[10];
  const float* opw  = (const float*)d_in[11];
  const float* nfw  = (const float*)d_in[12];
  const float* nfb  = (const float*)d_in[13];
  const float* hw   = (const float*)d_in[14];
  const int*   ids  = (const int*)d_in[15];
  const int*   labs = (const int*)d_in[16];
  float* out = (float*)d_out;

  char* ws = (char*)d_ws;
  float*          X    = (float*)(ws);                          // 8192x768 f32
  unsigned short* ZX   = (unsigned short*)(ws +  25165824ull);  // 8192x3224 bf16
  unsigned short* XC   = (unsigned short*)(ws +  77987840ull);  // 8192x1664 bf16
  unsigned short* Ybf  = (unsigned short*)(ws + 105250816ull);  // 8192x1536 bf16
  unsigned short* XNb  = (unsigned short*)(ws + 130416640ull);  // 8192x768 bf16
  unsigned short* IPWb = (unsigned short*)(ws + 142999552ull);  // 12x3224x768 bf16
  unsigned short* OPWb = (unsigned short*)(ws + 202424320ull);  // 12x768x1536 bf16 (x norm_w)
  unsigned short* HWb  = (unsigned short*)(ws + 230735872ull);  // 2048x768 bf16
  float2*         DTC  = (float2*)(ws + 233881600ull);          // 96x16x128 float2
  float*          CDEC = (float*)(ws + 235454464ull);           // 96x16 f32
  float*          RS   = (float*)(ws + 235460608ull);           // 8192 f32 (sumsq)
  float*          ACC  = (float*)(ws + 235493376ull);           // 1
  float*          HC   = out + 1;                               // 6.29M f32 (dead logits region)
  float*          HIN  = out + 1 + 6291456;                     // 6.29M f32

  embed_kernel<<<ROWS*DIMM/256, 256, 0, stream>>>(tok, pos, ids, X);
  {
    const int tot = NLAYER*DINP*DIMM/8 + NLAYER*DIMM*DINNER/8 + VOC*DIMM/8;
    cvtall_kernel<<<(tot + 255)/256, 256, 0, stream>>>(ipw, opw, nw, hw, IPWb, OPWb, HWb);
  }

  for (int l = 0; l < NLAYER; l++) {
    ln_kernel<<<ROWS, 256, 0, stream>>>(X, lnw + l*DIMM, lnb + l*DIMM, XNb);

    dim3 g1(64, 26);
    gemm_kernel<2><<<g1, 256, 0, stream>>>(XNb, IPWb + (size_t)l*DINP*DIMM, ZX, nullptr,
                                           DINP, DIMM, DIMM, DIMM, DINP);

    conv_kernel<<<ROWS*208/256, 256, 0, stream>>>(ZX, cw + l*CONVD*4, cb + l*CONVD, XC, RS);

    dim3 gs(NB*NCH, NH);
    chunkstate_kernel<<<gs, 256, 0, stream>>>(XC, ZX, dtb + l*NH, alog + l*NH, HC, DTC, CDEC);
    dim3 g2s(NB*NH, 4);
    scan2_kernel<<<g2s, 256, 0, stream>>>(HC, HIN, CDEC);
    ydec_kernel<<<gs, 256, 0, stream>>>(XC, ZX, DTC, HIN, dpar + l*NH, Ybf, RS);

    dim3 g2(64, 6);
    gemm_kernel<1><<<g2, 256, 0, stream>>>(Ybf, OPWb + (size_t)l*DIMM*DINNER, X, RS,
                                           DIMM, DINNER, DINNER, DINNER, DIMM);
  }

  ln_kernel<<<ROWS, 256, 0, stream>>>(X, nfw, nfb, XNb);
  dim3 g3(64, 16);
  gemm_kernel<0><<<g3, 256, 0, stream>>>(XNb, HWb, out + 1, nullptr,
                                         VOC, DIMM, DIMM, DIMM, VOC);

  zero_kernel<<<1, 1, 0, stream>>>(ACC);
  loss_kernel<<<2047, 256, 0, stream>>>(out + 1, labs, ACC);
  fin_kernel<<<1, 1, 0, stream>>>(out, ACC);
}